// Round 15
// baseline (2499.222 us; speedup 1.0000x reference)
//
#include <hip/hip_runtime.h>
#include <cmath>

// Problem constants
#define M 256
#define N 512
#define P 24
#define D 8

// ---------------------------------------------------------------------------
// self terms + folded weights at[i,u] = A[i,u]*exp(-0.5*||x_iu||^2).
// Block M+N writes the ones-column of Bc.
// ---------------------------------------------------------------------------
__global__ __launch_bounds__(64) void self_kernel(const float* __restrict__ X_test,
                                                  const float* __restrict__ A_test,
                                                  const float* __restrict__ X_obs,
                                                  const float* __restrict__ A_obs,
                                                  float* __restrict__ s1,
                                                  float* __restrict__ s2,
                                                  float* __restrict__ atT,
                                                  float* __restrict__ atO,
                                                  double* __restrict__ Bc) {
    const int bid = blockIdx.x;
    const int lane = threadIdx.x;
    if (bid == M + N) {  // ones column (col 256 of Bc, col-major [257][512])
#pragma unroll
        for (int t = 0; t < 8; ++t) Bc[(size_t)256 * 512 + 64 * t + lane] = 1.0;
        return;
    }
    const float* X; const float* A; float* s; float* at; int i;
    if (bid < M) { X = X_test; A = A_test; s = s1; at = atT; i = bid; }
    else         { X = X_obs;  A = A_obs;  s = s2; at = atO; i = bid - M; }
    const float* Xi = X + (size_t)i * P * D;
    const float* Ai = A + (size_t)i * P;
    float acc = 0.f;
#pragma unroll
    for (int t = 0; t < 9; ++t) {
        int idx = lane + 64 * t;          // 0..575
        int u = idx / 24;
        int v = idx - u * 24;
        const float* xu = Xi + u * D;
        const float* xv = Xi + v * D;
        float d2 = 0.f;
#pragma unroll
        for (int d = 0; d < D; ++d) { float df = xu[d] - xv[d]; d2 = fmaf(df, df, d2); }
        acc = fmaf(Ai[u] * Ai[v], __expf(-0.5f * d2), acc);
    }
#pragma unroll
    for (int off = 1; off < 64; off <<= 1) acc += __shfl_xor(acc, off, 64);
    if (lane == 0) s[i] = acc;
    if (lane < 24) {
        const float* xp = Xi + lane * D;
        float q = 0.f;
#pragma unroll
        for (int d = 0; d < D; ++d) q = fmaf(xp[d], xp[d], q);
        at[(size_t)i * P + lane] = Ai[lane] * __expf(-0.5f * q);
    }
}

// ---------------------------------------------------------------------------
// fused gram kernel with norm-folded weights (unchanged)
// ---------------------------------------------------------------------------
__global__ __launch_bounds__(128) void gram_kernel(
    const float* __restrict__ Xt, const float* __restrict__ atT, const float* __restrict__ s1,
    const float* __restrict__ Xo, const float* __restrict__ atO, const float* __restrict__ s2,
    const float* __restrict__ rho_p, const float* __restrict__ nu_p, const float* __restrict__ g_p,
    float* __restrict__ KoxT, float* __restrict__ Kxx, double* __restrict__ Koo,
    double* __restrict__ Bc) {
    const int mode = blockIdx.z;
    const int it = blockIdx.x, jt = blockIdx.y;
    const float *X1, *AT1, *S1, *X2, *AT2, *S2;
    if (mode == 0) {
        if (jt > 2 * it + 1) return;
        X1 = Xo; AT1 = atO; S1 = s2; X2 = Xo; AT2 = atO; S2 = s2;
    } else if (mode == 1) {
        if (jt >= 32) return;
        X1 = Xo; AT1 = atO; S1 = s2; X2 = Xt; AT2 = atT; S2 = s1;
    } else {
        if (it >= 16 || jt >= 32 || jt < 2 * it) return;
        X1 = Xt; AT1 = atT; S1 = s1; X2 = Xt; AT2 = atT; S2 = s1;
    }
    const int i0 = it * 16, j0 = jt * 8;
    const int tid = threadIdx.x;
    const int il = tid >> 3, uc = tid & 7;
    const int i = i0 + il;

    __shared__ __align__(16) float X2s[8 * 192];
    __shared__ float A2s[8 * 24];
    __shared__ float S2s[8];
    {
        const float4* gx = (const float4*)(X2 + (size_t)j0 * 192);
        float4* lx = (float4*)X2s;
        for (int idx = tid; idx < 8 * 48; idx += 128) lx[idx] = gx[idx];
        for (int idx = tid; idx < 8 * 24; idx += 128) A2s[idx] = AT2[(size_t)j0 * 24 + idx];
        if (tid < 8) S2s[tid] = S2[j0 + tid];
    }
    __syncthreads();

    float x1r[3][8], at1r[3];
#pragma unroll
    for (int ss = 0; ss < 3; ++ss) {
        const float* p = X1 + ((size_t)i * P + uc * 3 + ss) * D;
#pragma unroll
        for (int d = 0; d < D; ++d) x1r[ss][d] = p[d];
        at1r[ss] = AT1[(size_t)i * P + uc * 3 + ss];
    }
    const float s1i = S1[i];
    const float rho = rho_p[0], nu = nu_p[0], g = g_p[0];

    for (int jj = 0; jj < 8; ++jj) {
        const float* xb = X2s + jj * 192;
        float e0 = 0.f, e1 = 0.f, e2 = 0.f;
#pragma unroll 4
        for (int v = 0; v < 24; ++v) {
            const float4 q0 = ((const float4*)(xb + v * 8))[0];
            const float4 q1 = ((const float4*)(xb + v * 8))[1];
            float x2r[8];
            x2r[0] = q0.x; x2r[1] = q0.y; x2r[2] = q0.z; x2r[3] = q0.w;
            x2r[4] = q1.x; x2r[5] = q1.y; x2r[6] = q1.z; x2r[7] = q1.w;
            const float w2 = A2s[jj * 24 + v];
            float d0 = 0.f, d1 = 0.f, d2 = 0.f;
#pragma unroll
            for (int dd = 0; dd < 8; ++dd) {
                d0 = fmaf(x1r[0][dd], x2r[dd], d0);
                d1 = fmaf(x1r[1][dd], x2r[dd], d1);
                d2 = fmaf(x1r[2][dd], x2r[dd], d2);
            }
            e0 = fmaf(w2, __expf(d0), e0);
            e1 = fmaf(w2, __expf(d1), e1);
            e2 = fmaf(w2, __expf(d2), e2);
        }
        float acc = at1r[0] * e0;
        acc = fmaf(at1r[1], e1, acc);
        acc = fmaf(at1r[2], e2, acc);
        acc += __shfl_xor(acc, 1, 8);
        acc += __shfl_xor(acc, 2, 8);
        acc += __shfl_xor(acc, 4, 8);
        if (uc == 0) {
            const int j = j0 + jj;
            float d2p = fmaxf(s1i + S2s[jj] - 2.f * acc, 0.f);
            float kv = __expf(-0.5f * d2p / rho);
            if (mode == 0) {
                if (j <= i) Koo[(size_t)i * 512 + j] = (double)(nu * (kv + ((i == j) ? g : 0.f)));
            } else if (mode == 1) {
                float val = nu * kv;
                KoxT[(size_t)j * 512 + i] = val;
                Bc[(size_t)j * 512 + i] = (double)val;
            } else {
                float val = nu * kv;
                if (j >= i) {
                    Kxx[(size_t)i * 256 + j] = val;
                    if (j > i) Kxx[(size_t)j * 256 + i] = val;
                }
            }
        }
    }
}

// ---------------------------------------------------------------------------
// Conflict-free 64x64 f64 tile engine (r12, unchanged).
// ---------------------------------------------------------------------------
__device__ __forceinline__ double2 ld2t(const double* T, int r, int m) {
    return *(const double2*)(T + r * 64 + 2 * ((m ^ (r >> 2)) & 31));
}
__device__ __forceinline__ void st2t(double* T, int r, int m, double x, double y) {
    double2 v; v.x = x; v.y = y;
    *(double2*)(T + r * 64 + 2 * ((m ^ (r >> 2)) & 31)) = v;
}

__device__ void stage_tile(double* T, const double* G, int ldg, int nrows) {
    const int tid = threadIdx.x;
#pragma unroll
    for (int e = 0; e < 8; ++e) {
        int idx = tid + 256 * e, r = idx >> 5, m = idx & 31;
        double x = 0.0, y = 0.0;
        if (r < nrows) {
            double2 v = *(const double2*)(G + (size_t)r * ldg + 2 * m);
            x = v.x; y = v.y;
        }
        st2t(T, r, m, x, y);
    }
}
__device__ void stage_tile_f(double* T, const float* G, int ldg) {
    const int tid = threadIdx.x;
#pragma unroll
    for (int e = 0; e < 8; ++e) {
        int idx = tid + 256 * e, r = idx >> 5, m = idx & 31;
        float2 v = *(const float2*)(G + (size_t)r * ldg + 2 * m);
        st2t(T, r, m, (double)v.x, (double)v.y);
    }
}

// acc[r][c] += sum_t At[4ty+r][t] * Bt[4tx+c][t]
__device__ __forceinline__ void mac4x4(const double* At, const double* Bt,
                                       double acc[4][4], int tx, int ty) {
#pragma unroll 4
    for (int m = 0; m < 32; ++m) {
        double2 a[4], b[4];
#pragma unroll
        for (int j = 0; j < 4; ++j) a[j] = ld2t(At, 4 * ty + j, m);
#pragma unroll
        for (int j = 0; j < 4; ++j) b[j] = ld2t(Bt, 4 * tx + j, m);
#pragma unroll
        for (int r = 0; r < 4; ++r)
#pragma unroll
            for (int c = 0; c < 4; ++c)
                acc[r][c] = fma(a[r].y, b[c].y, fma(a[r].x, b[c].x, acc[r][c]));
    }
}

__device__ void stt_tile(double* T, const double v[4][4], int tx, int ty) {
#pragma unroll
    for (int r = 0; r < 4; ++r)
#pragma unroll
        for (int mp = 0; mp < 2; ++mp)
            st2t(T, 4 * ty + r, 2 * tx + mp, v[r][2 * mp], v[r][2 * mp + 1]);
}

#define LO(i, j) ((i) * ((i) + 1) / 2 + (j))   // packed lower-tile index (i>=j)

// ---------------------------------------------------------------------------
// fast f64 reciprocal / rsqrt via HW estimate + Newton.
// ---------------------------------------------------------------------------
__device__ __forceinline__ double frcp(double d) {
    double r;
    asm("v_rcp_f64 %0, %1" : "=v"(r) : "v"(d));
    double e = fma(-d, r, 1.0); r = fma(r, e, r);
    e = fma(-d, r, 1.0); r = fma(r, e, r);
    return r;
}
__device__ __forceinline__ double frsq(double d) {
    double r;
    asm("v_rsq_f64 %0, %1" : "=v"(r) : "v"(d));
    double t = -0.5 * d * r; r = r * fma(t, r, 1.5);
    t = -0.5 * d * r; r = r * fma(t, r, 1.5);
    return r;
}

// ---------------------------------------------------------------------------
// factor64 v4 — SMALL-CODE serial factor (r14 post-mortem: v3's fully
// unrolled body was ~60KB of straight-line code -> I-cache misses at L2
// latency dominated; VALU was idle). v4 keeps the matrix in LDS with
// runtime loops (#pragma unroll 1): body ~3KB, I-cache resident.
// Single wave (tid<64). sA [64][65] FULL (mirrored). sX [64][65] out.
// colbuf[64] scratch. Math identical to v3 (LDL + Newton rcp/rsqrt).
// ---------------------------------------------------------------------------
__device__ void factor64v4(double* sA, double* sX, double* colbuf,
                           double* __restrict__ Wp, double* __restrict__ WTp,
                           int p) {
    const int lane = threadIdx.x;
    double* myrow = sA + lane * 65;
    // LDL elimination: lane r sweeps its full row; pivot-row reads broadcast.
#pragma unroll 1
    for (int k = 0; k < 64; ++k) {
        const double* prow = sA + k * 65;
        double dk = prow[k];
        double inv = frcp(dk);
        if (lane == k) colbuf[k] = inv;
        double srow = (lane > k) ? myrow[k] * inv : 0.0;
#pragma unroll 1
        for (int c = k + 1; c < 64; ++c)
            myrow[c] = fma(-srow, prow[c], myrow[c]);
    }
    const double myd = myrow[lane];
    // scale columns to unit-lower Lu: Lu[r][c] = a[r][c] * invd_c (c < r)
#pragma unroll 1
    for (int c = 0; c < 64; ++c)
        if (c < lane) myrow[c] *= colbuf[c];
    const double myrs = frsq(myd);
    colbuf[lane] = myrs;                         // overwrite: now row scales
    // inverse of unit-lower Lu, column-per-lane. Lu reads broadcast.
#pragma unroll 1
    for (int r = 0; r < 64; ++r) {
        const double* Lr = sA + r * 65;
        double acc = 0.0;
#pragma unroll 1
        for (int t = 0; t < r; ++t) {
            double xv = sX[t * 65 + lane];
            double contrib = (t >= lane) ? Lr[t] * xv : 0.0;
            acc += contrib;
        }
        sX[r * 65 + lane] = (r == lane) ? 1.0 : ((r > lane) ? -acc : 0.0);
    }
    // X[r][c] = Yu[r][c] * rs_r ; write packed Wp (row-major) + WTp
    const size_t off = (size_t)LO(p, p) * 4096;
#pragma unroll 1
    for (int r = 0; r < 64; ++r)
        Wp[off + (size_t)r * 64 + lane] = sX[r * 65 + lane] * colbuf[r];
#pragma unroll 1
    for (int r = 0; r < 64; r += 2) {
        double2 v;
        v.x = sX[r * 65 + lane] * colbuf[r];
        v.y = sX[(r + 1) * 65 + lane] * colbuf[r + 1];
        *(double2*)(WTp + off + (size_t)lane * 64 + r) = v;
    }
}

// standalone factor dispatch: stage diag tile (p,p) of A (mirrored full), run v4
__global__ __launch_bounds__(256) void factor_kernel(const double* __restrict__ A,
                                                     double* __restrict__ Wp,
                                                     double* __restrict__ WTp,
                                                     int p) {
    __shared__ double smem[4160 + 4160 + 64];
    const int tid = threadIdx.x;
    const double* Ad = A + (size_t)p * 64 * 512 + (size_t)p * 64;
    for (int idx = tid; idx < 4096; idx += 256) {
        int r = idx >> 6, c = idx & 63;
        smem[r * 65 + c] = (c <= r) ? Ad[(size_t)r * 512 + c] : Ad[(size_t)c * 512 + r];
    }
    __syncthreads();
    if (tid < 64) factor64v4(smem, smem + 4160, smem + 8320, Wp, WTp, p);
}

// ---------------------------------------------------------------------------
// trailing-update tile for panel p: pure tile work (unchanged from r14).
// ---------------------------------------------------------------------------
__device__ void upd_tile(double* smem, double* A, double* LL,
                         double* Wp, double* WTp, int p, int s, int tx, int ty) {
    double* T0 = smem;
    double* T1 = smem + 4096;
    double* T2 = smem + 8192;
    int bi = 0;
    while (s >= bi + 1) { s -= bi + 1; ++bi; }
    const int bj = s;
    const int I = p + 1 + bi, J = p + 1 + bj;
    const bool diag = (I == J);

    stage_tile(T0, A + (size_t)I * 64 * 512 + p * 64, 512, 64);
    if (!diag) stage_tile(T1, A + (size_t)J * 64 * 512 + p * 64, 512, 64);
    stage_tile(T2, Wp + (size_t)LO(p, p) * 4096, 64, 64);   // Dinv_p: T2[c][t]=X[c][t]
    __syncthreads();

    double lip[4][4] = {}, ljp[4][4] = {};
    mac4x4(T0, T2, lip, tx, ty);                             // L_Ip = A_Ip · X^T
    if (!diag) mac4x4(T1, T2, ljp, tx, ty);
    __syncthreads();
    stt_tile(T0, lip, tx, ty);
    if (!diag) stt_tile(T1, ljp, tx, ty);
    if (diag) {                                              // publish L tile (I,p)
#pragma unroll
        for (int r = 0; r < 4; ++r)
#pragma unroll
            for (int c = 0; c < 4; ++c)
                LL[(size_t)(I * 64 + 4 * ty + r) * 512 + p * 64 + 4 * tx + c] = lip[r][c];
    }
    __syncthreads();

    double acc[4][4] = {};
    mac4x4(T0, diag ? T0 : T1, acc, tx, ty);                 // L_Ip · L_Jp^T

    double* Aij = A + (size_t)I * 64 * 512 + (size_t)J * 64;
#pragma unroll
    for (int r = 0; r < 4; ++r)
#pragma unroll
        for (int c = 0; c < 4; ++c) {
            int rr = 4 * ty + r, cc = 4 * tx + c;
            if (!diag || cc <= rr)
                Aij[(size_t)rr * 512 + cc] -= acc[r][c];
        }
}

// W row-panel p tile J (J<p): X_pJ = -Dinv_p * sum_{K=J..p-1} L_pK * X_KJ
__device__ void wrow_tile(double* smem, const double* LL,
                          double* Wp, double* WTp, int p, int J, int tx, int ty) {
    double* T0 = smem;
    double* T1 = smem + 4096;
    double* T2 = smem + 8192;
    stage_tile(T2, Wp + (size_t)LO(p, p) * 4096, 64, 64);    // Dinv_p
    double S[4][4] = {};
    for (int K = J; K < p; ++K) {
        stage_tile(T0, LL + (size_t)(p * 64) * 512 + K * 64, 512, 64);   // L_pK rows
        stage_tile(T1, WTp + (size_t)LO(K, J) * 4096, 64, 64);           // T1[a][b]=X_KJ[b][a]
        __syncthreads();
        mac4x4(T0, T1, S, tx, ty);                           // S += L_pK · X_KJ
        __syncthreads();
    }
    // store S transposed into T0: T0[c'][t'] = S_glob[t'][c']
#pragma unroll
    for (int c = 0; c < 4; ++c)
#pragma unroll
        for (int rp = 0; rp < 2; ++rp)
            st2t(T0, 4 * tx + c, 2 * ty + rp, S[2 * rp][c], S[2 * rp + 1][c]);
    __syncthreads();
    double X[4][4] = {};
    mac4x4(T2, T0, X, tx, ty);                               // Dinv_p · S
    const size_t wo = (size_t)LO(p, J) * 4096;
#pragma unroll
    for (int r = 0; r < 4; ++r)
#pragma unroll
        for (int c = 0; c < 4; ++c) {
            Wp[wo + (size_t)(4 * ty + r) * 64 + 4 * tx + c] = -X[r][c];
            WTp[wo + (size_t)(4 * tx + c) * 64 + 4 * ty + r] = -X[r][c];
        }
}

// upd launch p: blocks [0,nupd) trailing tiles; [nupd, nupd+p) W row-panel p
__global__ __launch_bounds__(256) void upd_kernel(double* __restrict__ A,
                                                  double* __restrict__ LL,
                                                  double* __restrict__ Wp,
                                                  double* __restrict__ WTp,
                                                  int p) {
    __shared__ double smem[12288];
    const int tx = threadIdx.x & 15, ty = threadIdx.x >> 4;
    const int nupd = (7 - p) * (8 - p) / 2;
    if ((int)blockIdx.x < nupd)
        upd_tile(smem, A, LL, Wp, WTp, p, blockIdx.x, tx, ty);
    else
        wrow_tile(smem, LL, Wp, WTp, p, blockIdx.x - nupd, tx, ty);
}

__global__ __launch_bounds__(256) void wrow7_kernel(const double* __restrict__ LL,
                                                    double* __restrict__ Wp,
                                                    double* __restrict__ WTp) {
    __shared__ double smem[12288];
    const int tx = threadIdx.x & 15, ty = threadIdx.x >> 4;
    wrow_tile(smem, LL, Wp, WTp, 7, blockIdx.x, tx, ty);
}

// ---------------------------------------------------------------------------
// GEMMs: T = W*B, then Z = W^T*T. B,T,Z col-major [col][512].
// ---------------------------------------------------------------------------
__global__ __launch_bounds__(256) void gemm1_kernel(const double* __restrict__ Wp,
                                                    const double* __restrict__ Bc,
                                                    double* __restrict__ Tbuf) {
    __shared__ double smem[8192];
    const int blk = blockIdx.x;
    const int i = blk / 5, ct = blk % 5, c0 = ct * 64;
    const int nr = (257 - c0 < 64) ? (257 - c0) : 64;
    double* T0 = smem;
    double* T1 = smem + 4096;
    const int tx = threadIdx.x & 15, ty = threadIdx.x >> 4;
    double acc[4][4] = {};
    for (int j = 0; j <= i; ++j) {
        stage_tile(T0, Wp + (size_t)LO(i, j) * 4096, 64, 64);
        stage_tile(T1, Bc + (size_t)c0 * 512 + j * 64, 512, nr);
        __syncthreads();
        mac4x4(T0, T1, acc, tx, ty);
        __syncthreads();
    }
#pragma unroll
    for (int r = 0; r < 4; ++r)
#pragma unroll
        for (int c = 0; c < 4; ++c) {
            int cc = c0 + 4 * tx + c;
            if (cc < 257) Tbuf[(size_t)cc * 512 + i * 64 + 4 * ty + r] = acc[r][c];
        }
}

__global__ __launch_bounds__(256) void gemm2_kernel(const double* __restrict__ WTp,
                                                    const double* __restrict__ Tbuf,
                                                    double* __restrict__ Bc) {
    __shared__ double smem[8192];
    const int blk = blockIdx.x;
    const int i = blk / 5, ct = blk % 5, c0 = ct * 64;
    const int nr = (257 - c0 < 64) ? (257 - c0) : 64;
    double* T0 = smem;
    double* T1 = smem + 4096;
    const int tx = threadIdx.x & 15, ty = threadIdx.x >> 4;
    double acc[4][4] = {};
    for (int j = i; j < 8; ++j) {
        stage_tile(T0, WTp + (size_t)LO(j, i) * 4096, 64, 64);   // T0[a][t]=W[j64+t][i64+a]
        stage_tile(T1, Tbuf + (size_t)c0 * 512 + j * 64, 512, nr);
        __syncthreads();
        mac4x4(T0, T1, acc, tx, ty);
        __syncthreads();
    }
#pragma unroll
    for (int r = 0; r < 4; ++r)
#pragma unroll
        for (int c = 0; c < 4; ++c) {
            int cc = c0 + 4 * tx + c;
            if (cc < 257) Bc[(size_t)cc * 512 + i * 64 + 4 * ty + r] = acc[r][c];
        }
}

// column reductions over Z (col-major [257][512]); 4 cols per block
__global__ __launch_bounds__(256) void colreduce_kernel(const double* __restrict__ Z,
                                                        const float* __restrict__ ys,
                                                        const float* __restrict__ b_p,
                                                        float* __restrict__ out,
                                                        double* __restrict__ kbx,
                                                        double* __restrict__ Sp) {
    const int lane = threadIdx.x & 63, w = threadIdx.x >> 6;
    const int c = blockIdx.x * 4 + w;
    if (c >= 257) return;
    const double b = (double)b_p[0];
    double s0 = 0.0, s1 = 0.0;
#pragma unroll
    for (int t = 0; t < 8; ++t) {
        int n = lane + 64 * t;
        double zv = Z[(size_t)c * 512 + n];
        s0 += zv;
        s1 = fma(zv, (double)ys[n] - b, s1);
    }
#pragma unroll
    for (int off = 1; off < 64; off <<= 1) {
        s0 += __shfl_xor(s0, off, 64);
        s1 += __shfl_xor(s1, off, 64);
    }
    if (lane == 0) {
        if (c < 256) { out[c] = (float)(b + s1); kbx[c] = s0; }
        else Sp[0] = s0;
    }
}

// cov[i][j] = Kxx[i][j] - sum_n Z[i][n]*Kox[n][j] + (1-kbx[i])(1-kbx[j])/S
__global__ __launch_bounds__(256) void cov_kernel(const double* __restrict__ Z,
                                                  const float* __restrict__ KoxT,
                                                  const float* __restrict__ Kxx,
                                                  const double* __restrict__ kbx,
                                                  const double* __restrict__ Sp,
                                                  float* __restrict__ out) {
    __shared__ double smem[8192];
    const int bi = blockIdx.x >> 2, bj = blockIdx.x & 3;
    double* T0 = smem;
    double* T1 = smem + 4096;
    const int tx = threadIdx.x & 15, ty = threadIdx.x >> 4;
    double acc[4][4] = {};
    for (int kt = 0; kt < 8; ++kt) {
        stage_tile(T0, Z + (size_t)(bi * 64) * 512 + kt * 64, 512, 64);
        stage_tile_f(T1, KoxT + (size_t)(bj * 64) * 512 + kt * 64, 512);
        __syncthreads();
        mac4x4(T0, T1, acc, tx, ty);
        __syncthreads();
    }
    const double S = Sp[0];
#pragma unroll
    for (int r = 0; r < 4; ++r) {
        int i = bi * 64 + 4 * ty + r;
        double ki = 1.0 - kbx[i];
#pragma unroll
        for (int c = 0; c < 4; ++c) {
            int j = bj * 64 + 4 * tx + c;
            double corr = ki * (1.0 - kbx[j]) / S;
            out[(size_t)(1 + i) * 256 + j] =
                (float)((double)Kxx[(size_t)i * 256 + j] - acc[r][c] + corr);
        }
    }
}

// ---------------------------------------------------------------------------
extern "C" void kernel_launch(void* const* d_in, const int* in_sizes, int n_in,
                              void* d_out, int out_size, void* d_ws, size_t ws_size,
                              hipStream_t stream) {
    const float* X_test = (const float*)d_in[0];
    const float* A_test = (const float*)d_in[1];
    const float* X_obs  = (const float*)d_in[2];
    const float* A_obs  = (const float*)d_in[3];
    const float* ys     = (const float*)d_in[4];
    const float* rho_p  = (const float*)d_in[5];
    const float* g_p    = (const float*)d_in[6];
    const float* nu_p   = (const float*)d_in[7];
    const float* b_p    = (const float*)d_in[8];
    float* out = (float*)d_out;
    char* ws = (char*)d_ws;

    double* Koo  = (double*)(ws + 0);         // 2,097,152 (A; Tbuf alias post-chol)
    double* LL   = (double*)(ws + 2097152);   // 2,097,152 (L row-major; atT/atO overlay pre-chol)
    double* Bc   = (double*)(ws + 4194304);   // 1,052,672 (RHS -> Z)
    float*  KoxT = (float*) (ws + 5246976);   // 524,288
    float*  Kxx  = (float*) (ws + 5771264);   // 262,144
    float*  s1v  = (float*) (ws + 6033408);   // 1,024
    float*  s2v  = (float*) (ws + 6034432);   // 2,048
    double* kbx  = (double*)(ws + 6036480);   // 2,048
    double* Sp   = (double*)(ws + 6038528);   // 1,024 (pad)
    double* Wp   = (double*)(ws + 6039552);   // 36*32768 = 1,179,648
    double* WTp  = (double*)(ws + 7219200);   // 1,179,648 (end 8,398,848)
    double* Tbuf = Koo;                       // aliases dead A after chol
    float*  atT  = (float*)(ws + 2097152);
    float*  atO  = (float*)(ws + 2097152 + 24576);

    self_kernel<<<M + N + 1, 64, 0, stream>>>(X_test, A_test, X_obs, A_obs,
                                              s1v, s2v, atT, atO, Bc);

    gram_kernel<<<dim3(32, 64, 3), 128, 0, stream>>>(X_test, atT, s1v,
                                                     X_obs, atO, s2v,
                                                     rho_p, nu_p, g_p,
                                                     KoxT, Kxx, Koo, Bc);

    factor_kernel<<<1, 256, 0, stream>>>(Koo, Wp, WTp, 0);
    for (int p = 0; p < 7; ++p) {
        int nb = (7 - p) * (8 - p) / 2 + p;   // trailing tiles + W row-panel p
        upd_kernel<<<nb, 256, 0, stream>>>(Koo, LL, Wp, WTp, p);
        factor_kernel<<<1, 256, 0, stream>>>(Koo, Wp, WTp, p + 1);
    }
    wrow7_kernel<<<7, 256, 0, stream>>>(LL, Wp, WTp);

    gemm1_kernel<<<40, 256, 0, stream>>>(Wp, Bc, Tbuf);
    gemm2_kernel<<<40, 256, 0, stream>>>(WTp, Tbuf, Bc);
    colreduce_kernel<<<65, 256, 0, stream>>>(Bc, ys, b_p, out, kbx, Sp);
    cov_kernel<<<16, 256, 0, stream>>>(Bc, KoxT, Kxx, kbx, Sp, out);
}

// Round 16
// 1342.229 us; speedup vs baseline: 1.8620x; 1.8620x over previous
//
#include <hip/hip_runtime.h>
#include <cmath>

// Problem constants
#define M 256
#define N 512
#define P 24
#define D 8

// ---------------------------------------------------------------------------
// self terms + folded weights at[i,u] = A[i,u]*exp(-0.5*||x_iu||^2).
// Block M+N writes the ones-column of Bc.
// ---------------------------------------------------------------------------
__global__ __launch_bounds__(64) void self_kernel(const float* __restrict__ X_test,
                                                  const float* __restrict__ A_test,
                                                  const float* __restrict__ X_obs,
                                                  const float* __restrict__ A_obs,
                                                  float* __restrict__ s1,
                                                  float* __restrict__ s2,
                                                  float* __restrict__ atT,
                                                  float* __restrict__ atO,
                                                  double* __restrict__ Bc) {
    const int bid = blockIdx.x;
    const int lane = threadIdx.x;
    if (bid == M + N) {  // ones column (col 256 of Bc, col-major [257][512])
#pragma unroll
        for (int t = 0; t < 8; ++t) Bc[(size_t)256 * 512 + 64 * t + lane] = 1.0;
        return;
    }
    const float* X; const float* A; float* s; float* at; int i;
    if (bid < M) { X = X_test; A = A_test; s = s1; at = atT; i = bid; }
    else         { X = X_obs;  A = A_obs;  s = s2; at = atO; i = bid - M; }
    const float* Xi = X + (size_t)i * P * D;
    const float* Ai = A + (size_t)i * P;
    float acc = 0.f;
#pragma unroll
    for (int t = 0; t < 9; ++t) {
        int idx = lane + 64 * t;          // 0..575
        int u = idx / 24;
        int v = idx - u * 24;
        const float* xu = Xi + u * D;
        const float* xv = Xi + v * D;
        float d2 = 0.f;
#pragma unroll
        for (int d = 0; d < D; ++d) { float df = xu[d] - xv[d]; d2 = fmaf(df, df, d2); }
        acc = fmaf(Ai[u] * Ai[v], __expf(-0.5f * d2), acc);
    }
#pragma unroll
    for (int off = 1; off < 64; off <<= 1) acc += __shfl_xor(acc, off, 64);
    if (lane == 0) s[i] = acc;
    if (lane < 24) {
        const float* xp = Xi + lane * D;
        float q = 0.f;
#pragma unroll
        for (int d = 0; d < D; ++d) q = fmaf(xp[d], xp[d], q);
        at[(size_t)i * P + lane] = Ai[lane] * __expf(-0.5f * q);
    }
}

// ---------------------------------------------------------------------------
// fused gram kernel with norm-folded weights (unchanged)
// ---------------------------------------------------------------------------
__global__ __launch_bounds__(128) void gram_kernel(
    const float* __restrict__ Xt, const float* __restrict__ atT, const float* __restrict__ s1,
    const float* __restrict__ Xo, const float* __restrict__ atO, const float* __restrict__ s2,
    const float* __restrict__ rho_p, const float* __restrict__ nu_p, const float* __restrict__ g_p,
    float* __restrict__ KoxT, float* __restrict__ Kxx, double* __restrict__ Koo,
    double* __restrict__ Bc) {
    const int mode = blockIdx.z;
    const int it = blockIdx.x, jt = blockIdx.y;
    const float *X1, *AT1, *S1, *X2, *AT2, *S2;
    if (mode == 0) {
        if (jt > 2 * it + 1) return;
        X1 = Xo; AT1 = atO; S1 = s2; X2 = Xo; AT2 = atO; S2 = s2;
    } else if (mode == 1) {
        if (jt >= 32) return;
        X1 = Xo; AT1 = atO; S1 = s2; X2 = Xt; AT2 = atT; S2 = s1;
    } else {
        if (it >= 16 || jt >= 32 || jt < 2 * it) return;
        X1 = Xt; AT1 = atT; S1 = s1; X2 = Xt; AT2 = atT; S2 = s1;
    }
    const int i0 = it * 16, j0 = jt * 8;
    const int tid = threadIdx.x;
    const int il = tid >> 3, uc = tid & 7;
    const int i = i0 + il;

    __shared__ __align__(16) float X2s[8 * 192];
    __shared__ float A2s[8 * 24];
    __shared__ float S2s[8];
    {
        const float4* gx = (const float4*)(X2 + (size_t)j0 * 192);
        float4* lx = (float4*)X2s;
        for (int idx = tid; idx < 8 * 48; idx += 128) lx[idx] = gx[idx];
        for (int idx = tid; idx < 8 * 24; idx += 128) A2s[idx] = AT2[(size_t)j0 * 24 + idx];
        if (tid < 8) S2s[tid] = S2[j0 + tid];
    }
    __syncthreads();

    float x1r[3][8], at1r[3];
#pragma unroll
    for (int ss = 0; ss < 3; ++ss) {
        const float* p = X1 + ((size_t)i * P + uc * 3 + ss) * D;
#pragma unroll
        for (int d = 0; d < D; ++d) x1r[ss][d] = p[d];
        at1r[ss] = AT1[(size_t)i * P + uc * 3 + ss];
    }
    const float s1i = S1[i];
    const float rho = rho_p[0], nu = nu_p[0], g = g_p[0];

    for (int jj = 0; jj < 8; ++jj) {
        const float* xb = X2s + jj * 192;
        float e0 = 0.f, e1 = 0.f, e2 = 0.f;
#pragma unroll 4
        for (int v = 0; v < 24; ++v) {
            const float4 q0 = ((const float4*)(xb + v * 8))[0];
            const float4 q1 = ((const float4*)(xb + v * 8))[1];
            float x2r[8];
            x2r[0] = q0.x; x2r[1] = q0.y; x2r[2] = q0.z; x2r[3] = q0.w;
            x2r[4] = q1.x; x2r[5] = q1.y; x2r[6] = q1.z; x2r[7] = q1.w;
            const float w2 = A2s[jj * 24 + v];
            float d0 = 0.f, d1 = 0.f, d2 = 0.f;
#pragma unroll
            for (int dd = 0; dd < 8; ++dd) {
                d0 = fmaf(x1r[0][dd], x2r[dd], d0);
                d1 = fmaf(x1r[1][dd], x2r[dd], d1);
                d2 = fmaf(x1r[2][dd], x2r[dd], d2);
            }
            e0 = fmaf(w2, __expf(d0), e0);
            e1 = fmaf(w2, __expf(d1), e1);
            e2 = fmaf(w2, __expf(d2), e2);
        }
        float acc = at1r[0] * e0;
        acc = fmaf(at1r[1], e1, acc);
        acc = fmaf(at1r[2], e2, acc);
        acc += __shfl_xor(acc, 1, 8);
        acc += __shfl_xor(acc, 2, 8);
        acc += __shfl_xor(acc, 4, 8);
        if (uc == 0) {
            const int j = j0 + jj;
            float d2p = fmaxf(s1i + S2s[jj] - 2.f * acc, 0.f);
            float kv = __expf(-0.5f * d2p / rho);
            if (mode == 0) {
                if (j <= i) Koo[(size_t)i * 512 + j] = (double)(nu * (kv + ((i == j) ? g : 0.f)));
            } else if (mode == 1) {
                float val = nu * kv;
                KoxT[(size_t)j * 512 + i] = val;
                Bc[(size_t)j * 512 + i] = (double)val;
            } else {
                float val = nu * kv;
                if (j >= i) {
                    Kxx[(size_t)i * 256 + j] = val;
                    if (j > i) Kxx[(size_t)j * 256 + i] = val;
                }
            }
        }
    }
}

// ---------------------------------------------------------------------------
// Conflict-free 64x64 f64 tile engine (r12, unchanged).
// ---------------------------------------------------------------------------
__device__ __forceinline__ double2 ld2t(const double* T, int r, int m) {
    return *(const double2*)(T + r * 64 + 2 * ((m ^ (r >> 2)) & 31));
}
__device__ __forceinline__ void st2t(double* T, int r, int m, double x, double y) {
    double2 v; v.x = x; v.y = y;
    *(double2*)(T + r * 64 + 2 * ((m ^ (r >> 2)) & 31)) = v;
}

__device__ void stage_tile(double* T, const double* G, int ldg, int nrows) {
    const int tid = threadIdx.x;
#pragma unroll
    for (int e = 0; e < 8; ++e) {
        int idx = tid + 256 * e, r = idx >> 5, m = idx & 31;
        double x = 0.0, y = 0.0;
        if (r < nrows) {
            double2 v = *(const double2*)(G + (size_t)r * ldg + 2 * m);
            x = v.x; y = v.y;
        }
        st2t(T, r, m, x, y);
    }
}
__device__ void stage_tile_f(double* T, const float* G, int ldg) {
    const int tid = threadIdx.x;
#pragma unroll
    for (int e = 0; e < 8; ++e) {
        int idx = tid + 256 * e, r = idx >> 5, m = idx & 31;
        float2 v = *(const float2*)(G + (size_t)r * ldg + 2 * m);
        st2t(T, r, m, (double)v.x, (double)v.y);
    }
}

// acc[r][c] += sum_t At[4ty+r][t] * Bt[4tx+c][t]
__device__ __forceinline__ void mac4x4(const double* At, const double* Bt,
                                       double acc[4][4], int tx, int ty) {
#pragma unroll 4
    for (int m = 0; m < 32; ++m) {
        double2 a[4], b[4];
#pragma unroll
        for (int j = 0; j < 4; ++j) a[j] = ld2t(At, 4 * ty + j, m);
#pragma unroll
        for (int j = 0; j < 4; ++j) b[j] = ld2t(Bt, 4 * tx + j, m);
#pragma unroll
        for (int r = 0; r < 4; ++r)
#pragma unroll
            for (int c = 0; c < 4; ++c)
                acc[r][c] = fma(a[r].y, b[c].y, fma(a[r].x, b[c].x, acc[r][c]));
    }
}

__device__ void stt_tile(double* T, const double v[4][4], int tx, int ty) {
#pragma unroll
    for (int r = 0; r < 4; ++r)
#pragma unroll
        for (int mp = 0; mp < 2; ++mp)
            st2t(T, 4 * ty + r, 2 * tx + mp, v[r][2 * mp], v[r][2 * mp + 1]);
}

#define LO(i, j) ((i) * ((i) + 1) / 2 + (j))   // packed lower-tile index (i>=j)

// ---------------------------------------------------------------------------
// fast f64 reciprocal / rsqrt via HW estimate + Newton.
// ---------------------------------------------------------------------------
__device__ __forceinline__ double frcp(double d) {
    double r;
    asm("v_rcp_f64 %0, %1" : "=v"(r) : "v"(d));
    double e = fma(-d, r, 1.0); r = fma(r, e, r);
    e = fma(-d, r, 1.0); r = fma(r, e, r);
    return r;
}
__device__ __forceinline__ double frsq(double d) {
    double r;
    asm("v_rsq_f64 %0, %1" : "=v"(r) : "v"(d));
    double t = -0.5 * d * r; r = r * fma(t, r, 1.5);
    t = -0.5 * d * r; r = r * fma(t, r, 1.5);
    return r;
}

// ---------------------------------------------------------------------------
// factor64 v5 — 256-thread parallel-per-step factor (r15 post-mortem:
// v3 = I-cache-bound giant unroll; v4 = 1-wave dependent-LDS latency chain.
// v5 = small code AND parallel LDS throughput + per-step barriers).
// Elimination: thread (r=tid&63, g=tid>>6) owns row r, col chunk [16g,16g+16);
// lower triangle only, deferred-scale LDL, Newton rcp. 64 steps.
// Inverse: column-per-lane (c=tid&63), 4 threads/column by row stripe q.
// sA [64][65] lower-valid; sX [64][65]; cb[128] (invd | rs).
// Writes X = inv(L_chol) to packed Wp/WTp tile p. All 256 threads enter.
// ---------------------------------------------------------------------------
__device__ void factor64v5(double* sA, double* sX, double* cb,
                           double* __restrict__ Wp, double* __restrict__ WTp,
                           int p) {
    const int tid = threadIdx.x;
    const int r = tid & 63, g = tid >> 6, c0 = 16 * g;
    // LDL elimination (lower triangle), one barrier per pivot
#pragma unroll 1
    for (int k = 0; k < 64; ++k) {
        double inv = frcp(sA[k * 65 + k]);
        double s = (r > k) ? sA[r * 65 + k] * inv : 0.0;
#pragma unroll 1
        for (int c = c0; c < c0 + 16; ++c)
            if (c > k && c <= r)
                sA[r * 65 + c] = fma(-s, sA[c * 65 + k], sA[r * 65 + c]);
        __syncthreads();
    }
    // invd, rs; zero sX
    if (tid < 64) {
        double d = sA[tid * 65 + tid];
        cb[tid] = frcp(d);
        cb[64 + tid] = frsq(d);
    }
#pragma unroll 1
    for (int i = tid; i < 4160; i += 256) sX[i] = 0.0;
    __syncthreads();
    // scale lower to unit-lower Lu; set sX diag
#pragma unroll 1
    for (int c = c0; c < c0 + 16; ++c)
        if (c < r) sA[r * 65 + c] *= cb[c];
    if (tid < 64) sX[tid * 65 + tid] = 1.0;
    __syncthreads();
    // inverse of Lu: column-parallel deferred GE
    {
        const int c = tid & 63, q = tid >> 6;
#pragma unroll 1
        for (int t = 0; t < 63; ++t) {
            double xt = sX[t * 65 + c];
            int rs0 = t + 1 + ((q - (t + 1)) & 3);
#pragma unroll 1
            for (int rr = rs0; rr < 64; rr += 4)
                sX[rr * 65 + c] = fma(-sA[rr * 65 + t], xt, sX[rr * 65 + c]);
            __syncthreads();
        }
        // X[r][c] = Yu[r][c] * rs_r; write packed Wp (row-major) + WTp
        const size_t off = (size_t)LO(p, p) * 4096;
#pragma unroll 1
        for (int rr = q; rr < 64; rr += 4) {
            double xv = sX[rr * 65 + c] * cb[64 + rr];
            Wp[off + (size_t)rr * 64 + c] = xv;
            WTp[off + (size_t)c * 64 + rr] = xv;
        }
    }
}

// factor of panel 0 (standalone): stage lower triangle, run v5
__global__ __launch_bounds__(256) void factor0_kernel(const double* __restrict__ A,
                                                      double* __restrict__ Wp,
                                                      double* __restrict__ WTp) {
    __shared__ double smem[4160 + 4160 + 128];
    const int tid = threadIdx.x;
    for (int idx = tid; idx < 4096; idx += 256) {
        int r = idx >> 6, c = idx & 63;
        if (c <= r) smem[r * 65 + c] = A[(size_t)r * 512 + c];
    }
    __syncthreads();
    factor64v5(smem, smem + 4160, smem + 8320, Wp, WTp, 0);
}

// ---------------------------------------------------------------------------
// trailing-update tile for panel p; block (0,0) factors panel p+1 in place
// (embedded, r13-proven pattern) via factor64v5.
// ---------------------------------------------------------------------------
__device__ void upd_tile(double* smem, double* A, double* LL,
                         double* Wp, double* WTp, int p, int s, int tx, int ty) {
    double* T0 = smem;
    double* T1 = smem + 4096;
    double* T2 = smem + 8192;
    int bi = 0;
    while (s >= bi + 1) { s -= bi + 1; ++bi; }
    const int bj = s;
    const int I = p + 1 + bi, J = p + 1 + bj;
    const bool diag = (I == J);

    stage_tile(T0, A + (size_t)I * 64 * 512 + p * 64, 512, 64);
    if (!diag) stage_tile(T1, A + (size_t)J * 64 * 512 + p * 64, 512, 64);
    stage_tile(T2, Wp + (size_t)LO(p, p) * 4096, 64, 64);   // Dinv_p: T2[c][t]=X[c][t]
    __syncthreads();

    double lip[4][4] = {}, ljp[4][4] = {};
    mac4x4(T0, T2, lip, tx, ty);                             // L_Ip = A_Ip · X^T
    if (!diag) mac4x4(T1, T2, ljp, tx, ty);
    __syncthreads();
    stt_tile(T0, lip, tx, ty);
    if (!diag) stt_tile(T1, ljp, tx, ty);
    if (diag) {                                              // publish L tile (I,p)
#pragma unroll
        for (int r = 0; r < 4; ++r)
#pragma unroll
            for (int c = 0; c < 4; ++c)
                LL[(size_t)(I * 64 + 4 * ty + r) * 512 + p * 64 + 4 * tx + c] = lip[r][c];
    }
    __syncthreads();

    double acc[4][4] = {};
    mac4x4(T0, diag ? T0 : T1, acc, tx, ty);                 // L_Ip · L_Jp^T

    double* Aij = A + (size_t)I * 64 * 512 + (size_t)J * 64;
    if (bi == 0 && bj == 0) {
        // factor panel p+1 in place: write updated diag tile (lower) into sA
        __syncthreads();
#pragma unroll
        for (int r = 0; r < 4; ++r)
#pragma unroll
            for (int c = 0; c < 4; ++c) {
                int rr = 4 * ty + r, cc = 4 * tx + c;
                if (cc <= rr) smem[rr * 65 + cc] = Aij[(size_t)rr * 512 + cc] - acc[r][c];
            }
        __syncthreads();
        factor64v5(smem, smem + 4160, smem + 8320, Wp, WTp, p + 1);
    } else {
#pragma unroll
        for (int r = 0; r < 4; ++r)
#pragma unroll
            for (int c = 0; c < 4; ++c) {
                int rr = 4 * ty + r, cc = 4 * tx + c;
                if (!diag || cc <= rr)
                    Aij[(size_t)rr * 512 + cc] -= acc[r][c];
            }
    }
}

// W row-panel p tile J (J<p): X_pJ = -Dinv_p * sum_{K=J..p-1} L_pK * X_KJ
__device__ void wrow_tile(double* smem, const double* LL,
                          double* Wp, double* WTp, int p, int J, int tx, int ty) {
    double* T0 = smem;
    double* T1 = smem + 4096;
    double* T2 = smem + 8192;
    stage_tile(T2, Wp + (size_t)LO(p, p) * 4096, 64, 64);    // Dinv_p
    double S[4][4] = {};
    for (int K = J; K < p; ++K) {
        stage_tile(T0, LL + (size_t)(p * 64) * 512 + K * 64, 512, 64);   // L_pK rows
        stage_tile(T1, WTp + (size_t)LO(K, J) * 4096, 64, 64);           // T1[a][b]=X_KJ[b][a]
        __syncthreads();
        mac4x4(T0, T1, S, tx, ty);                           // S += L_pK · X_KJ
        __syncthreads();
    }
    // store S transposed into T0: T0[c'][t'] = S_glob[t'][c']
#pragma unroll
    for (int c = 0; c < 4; ++c)
#pragma unroll
        for (int rp = 0; rp < 2; ++rp)
            st2t(T0, 4 * tx + c, 2 * ty + rp, S[2 * rp][c], S[2 * rp + 1][c]);
    __syncthreads();
    double X[4][4] = {};
    mac4x4(T2, T0, X, tx, ty);                               // Dinv_p · S
    const size_t wo = (size_t)LO(p, J) * 4096;
#pragma unroll
    for (int r = 0; r < 4; ++r)
#pragma unroll
        for (int c = 0; c < 4; ++c) {
            Wp[wo + (size_t)(4 * ty + r) * 64 + 4 * tx + c] = -X[r][c];
            WTp[wo + (size_t)(4 * tx + c) * 64 + 4 * ty + r] = -X[r][c];
        }
}

// upd launch p: blocks [0,nupd) trailing tiles; [nupd, nupd+p) W row-panel p
__global__ __launch_bounds__(256) void upd_kernel(double* __restrict__ A,
                                                  double* __restrict__ LL,
                                                  double* __restrict__ Wp,
                                                  double* __restrict__ WTp,
                                                  int p) {
    __shared__ double smem[12288];
    const int tx = threadIdx.x & 15, ty = threadIdx.x >> 4;
    const int nupd = (7 - p) * (8 - p) / 2;
    if ((int)blockIdx.x < nupd)
        upd_tile(smem, A, LL, Wp, WTp, p, blockIdx.x, tx, ty);
    else
        wrow_tile(smem, LL, Wp, WTp, p, blockIdx.x - nupd, tx, ty);
}

__global__ __launch_bounds__(256) void wrow7_kernel(const double* __restrict__ LL,
                                                    double* __restrict__ Wp,
                                                    double* __restrict__ WTp) {
    __shared__ double smem[12288];
    const int tx = threadIdx.x & 15, ty = threadIdx.x >> 4;
    wrow_tile(smem, LL, Wp, WTp, 7, blockIdx.x, tx, ty);
}

// ---------------------------------------------------------------------------
// GEMMs: T = W*B, then Z = W^T*T. B,T,Z col-major [col][512].
// ---------------------------------------------------------------------------
__global__ __launch_bounds__(256) void gemm1_kernel(const double* __restrict__ Wp,
                                                    const double* __restrict__ Bc,
                                                    double* __restrict__ Tbuf) {
    __shared__ double smem[8192];
    const int blk = blockIdx.x;
    const int i = blk / 5, ct = blk % 5, c0 = ct * 64;
    const int nr = (257 - c0 < 64) ? (257 - c0) : 64;
    double* T0 = smem;
    double* T1 = smem + 4096;
    const int tx = threadIdx.x & 15, ty = threadIdx.x >> 4;
    double acc[4][4] = {};
    for (int j = 0; j <= i; ++j) {
        stage_tile(T0, Wp + (size_t)LO(i, j) * 4096, 64, 64);
        stage_tile(T1, Bc + (size_t)c0 * 512 + j * 64, 512, nr);
        __syncthreads();
        mac4x4(T0, T1, acc, tx, ty);
        __syncthreads();
    }
#pragma unroll
    for (int r = 0; r < 4; ++r)
#pragma unroll
        for (int c = 0; c < 4; ++c) {
            int cc = c0 + 4 * tx + c;
            if (cc < 257) Tbuf[(size_t)cc * 512 + i * 64 + 4 * ty + r] = acc[r][c];
        }
}

__global__ __launch_bounds__(256) void gemm2_kernel(const double* __restrict__ WTp,
                                                    const double* __restrict__ Tbuf,
                                                    double* __restrict__ Bc) {
    __shared__ double smem[8192];
    const int blk = blockIdx.x;
    const int i = blk / 5, ct = blk % 5, c0 = ct * 64;
    const int nr = (257 - c0 < 64) ? (257 - c0) : 64;
    double* T0 = smem;
    double* T1 = smem + 4096;
    const int tx = threadIdx.x & 15, ty = threadIdx.x >> 4;
    double acc[4][4] = {};
    for (int j = i; j < 8; ++j) {
        stage_tile(T0, WTp + (size_t)LO(j, i) * 4096, 64, 64);   // T0[a][t]=W[j64+t][i64+a]
        stage_tile(T1, Tbuf + (size_t)c0 * 512 + j * 64, 512, nr);
        __syncthreads();
        mac4x4(T0, T1, acc, tx, ty);
        __syncthreads();
    }
#pragma unroll
    for (int r = 0; r < 4; ++r)
#pragma unroll
        for (int c = 0; c < 4; ++c) {
            int cc = c0 + 4 * tx + c;
            if (cc < 257) Bc[(size_t)cc * 512 + i * 64 + 4 * ty + r] = acc[r][c];
        }
}

// column reductions over Z (col-major [257][512]); 4 cols per block
__global__ __launch_bounds__(256) void colreduce_kernel(const double* __restrict__ Z,
                                                        const float* __restrict__ ys,
                                                        const float* __restrict__ b_p,
                                                        float* __restrict__ out,
                                                        double* __restrict__ kbx,
                                                        double* __restrict__ Sp) {
    const int lane = threadIdx.x & 63, w = threadIdx.x >> 6;
    const int c = blockIdx.x * 4 + w;
    if (c >= 257) return;
    const double b = (double)b_p[0];
    double s0 = 0.0, s1 = 0.0;
#pragma unroll
    for (int t = 0; t < 8; ++t) {
        int n = lane + 64 * t;
        double zv = Z[(size_t)c * 512 + n];
        s0 += zv;
        s1 = fma(zv, (double)ys[n] - b, s1);
    }
#pragma unroll
    for (int off = 1; off < 64; off <<= 1) {
        s0 += __shfl_xor(s0, off, 64);
        s1 += __shfl_xor(s1, off, 64);
    }
    if (lane == 0) {
        if (c < 256) { out[c] = (float)(b + s1); kbx[c] = s0; }
        else Sp[0] = s0;
    }
}

// cov[i][j] = Kxx[i][j] - sum_n Z[i][n]*Kox[n][j] + (1-kbx[i])(1-kbx[j])/S
__global__ __launch_bounds__(256) void cov_kernel(const double* __restrict__ Z,
                                                  const float* __restrict__ KoxT,
                                                  const float* __restrict__ Kxx,
                                                  const double* __restrict__ kbx,
                                                  const double* __restrict__ Sp,
                                                  float* __restrict__ out) {
    __shared__ double smem[8192];
    const int bi = blockIdx.x >> 2, bj = blockIdx.x & 3;
    double* T0 = smem;
    double* T1 = smem + 4096;
    const int tx = threadIdx.x & 15, ty = threadIdx.x >> 4;
    double acc[4][4] = {};
    for (int kt = 0; kt < 8; ++kt) {
        stage_tile(T0, Z + (size_t)(bi * 64) * 512 + kt * 64, 512, 64);
        stage_tile_f(T1, KoxT + (size_t)(bj * 64) * 512 + kt * 64, 512);
        __syncthreads();
        mac4x4(T0, T1, acc, tx, ty);
        __syncthreads();
    }
    const double S = Sp[0];
#pragma unroll
    for (int r = 0; r < 4; ++r) {
        int i = bi * 64 + 4 * ty + r;
        double ki = 1.0 - kbx[i];
#pragma unroll
        for (int c = 0; c < 4; ++c) {
            int j = bj * 64 + 4 * tx + c;
            double corr = ki * (1.0 - kbx[j]) / S;
            out[(size_t)(1 + i) * 256 + j] =
                (float)((double)Kxx[(size_t)i * 256 + j] - acc[r][c] + corr);
        }
    }
}

// ---------------------------------------------------------------------------
extern "C" void kernel_launch(void* const* d_in, const int* in_sizes, int n_in,
                              void* d_out, int out_size, void* d_ws, size_t ws_size,
                              hipStream_t stream) {
    const float* X_test = (const float*)d_in[0];
    const float* A_test = (const float*)d_in[1];
    const float* X_obs  = (const float*)d_in[2];
    const float* A_obs  = (const float*)d_in[3];
    const float* ys     = (const float*)d_in[4];
    const float* rho_p  = (const float*)d_in[5];
    const float* g_p    = (const float*)d_in[6];
    const float* nu_p   = (const float*)d_in[7];
    const float* b_p    = (const float*)d_in[8];
    float* out = (float*)d_out;
    char* ws = (char*)d_ws;

    double* Koo  = (double*)(ws + 0);         // 2,097,152 (A; Tbuf alias post-chol)
    double* LL   = (double*)(ws + 2097152);   // 2,097,152 (L row-major; atT/atO overlay pre-chol)
    double* Bc   = (double*)(ws + 4194304);   // 1,052,672 (RHS -> Z)
    float*  KoxT = (float*) (ws + 5246976);   // 524,288
    float*  Kxx  = (float*) (ws + 5771264);   // 262,144
    float*  s1v  = (float*) (ws + 6033408);   // 1,024
    float*  s2v  = (float*) (ws + 6034432);   // 2,048
    double* kbx  = (double*)(ws + 6036480);   // 2,048
    double* Sp   = (double*)(ws + 6038528);   // 1,024 (pad)
    double* Wp   = (double*)(ws + 6039552);   // 36*32768 = 1,179,648
    double* WTp  = (double*)(ws + 7219200);   // 1,179,648 (end 8,398,848)
    double* Tbuf = Koo;                       // aliases dead A after chol
    float*  atT  = (float*)(ws + 2097152);
    float*  atO  = (float*)(ws + 2097152 + 24576);

    self_kernel<<<M + N + 1, 64, 0, stream>>>(X_test, A_test, X_obs, A_obs,
                                              s1v, s2v, atT, atO, Bc);

    gram_kernel<<<dim3(32, 64, 3), 128, 0, stream>>>(X_test, atT, s1v,
                                                     X_obs, atO, s2v,
                                                     rho_p, nu_p, g_p,
                                                     KoxT, Kxx, Koo, Bc);

    factor0_kernel<<<1, 256, 0, stream>>>(Koo, Wp, WTp);
    for (int p = 0; p < 7; ++p) {
        int nb = (7 - p) * (8 - p) / 2 + p;   // trailing tiles + W row-panel p
        upd_kernel<<<nb, 256, 0, stream>>>(Koo, LL, Wp, WTp, p);
    }
    wrow7_kernel<<<7, 256, 0, stream>>>(LL, Wp, WTp);

    gemm1_kernel<<<40, 256, 0, stream>>>(Wp, Bc, Tbuf);
    gemm2_kernel<<<40, 256, 0, stream>>>(WTp, Tbuf, Bc);
    colreduce_kernel<<<65, 256, 0, stream>>>(Bc, ys, b_p, out, kbx, Sp);
    cov_kernel<<<16, 256, 0, stream>>>(Bc, KoxT, Kxx, kbx, Sp, out);
}

// Round 17
// 1261.114 us; speedup vs baseline: 1.9818x; 1.0643x over previous
//
#include <hip/hip_runtime.h>
#include <cmath>

// Problem constants
#define M 256
#define N 512
#define P 24
#define D 8

// ---------------------------------------------------------------------------
// self terms + folded weights at[i,u] = A[i,u]*exp(-0.5*||x_iu||^2).
// Block M+N writes the ones-column of Bc.
// ---------------------------------------------------------------------------
__global__ __launch_bounds__(64) void self_kernel(const float* __restrict__ X_test,
                                                  const float* __restrict__ A_test,
                                                  const float* __restrict__ X_obs,
                                                  const float* __restrict__ A_obs,
                                                  float* __restrict__ s1,
                                                  float* __restrict__ s2,
                                                  float* __restrict__ atT,
                                                  float* __restrict__ atO,
                                                  double* __restrict__ Bc) {
    const int bid = blockIdx.x;
    const int lane = threadIdx.x;
    if (bid == M + N) {  // ones column (col 256 of Bc, col-major [257][512])
#pragma unroll
        for (int t = 0; t < 8; ++t) Bc[(size_t)256 * 512 + 64 * t + lane] = 1.0;
        return;
    }
    const float* X; const float* A; float* s; float* at; int i;
    if (bid < M) { X = X_test; A = A_test; s = s1; at = atT; i = bid; }
    else         { X = X_obs;  A = A_obs;  s = s2; at = atO; i = bid - M; }
    const float* Xi = X + (size_t)i * P * D;
    const float* Ai = A + (size_t)i * P;
    float acc = 0.f;
#pragma unroll
    for (int t = 0; t < 9; ++t) {
        int idx = lane + 64 * t;          // 0..575
        int u = idx / 24;
        int v = idx - u * 24;
        const float* xu = Xi + u * D;
        const float* xv = Xi + v * D;
        float d2 = 0.f;
#pragma unroll
        for (int d = 0; d < D; ++d) { float df = xu[d] - xv[d]; d2 = fmaf(df, df, d2); }
        acc = fmaf(Ai[u] * Ai[v], __expf(-0.5f * d2), acc);
    }
#pragma unroll
    for (int off = 1; off < 64; off <<= 1) acc += __shfl_xor(acc, off, 64);
    if (lane == 0) s[i] = acc;
    if (lane < 24) {
        const float* xp = Xi + lane * D;
        float q = 0.f;
#pragma unroll
        for (int d = 0; d < D; ++d) q = fmaf(xp[d], xp[d], q);
        at[(size_t)i * P + lane] = Ai[lane] * __expf(-0.5f * q);
    }
}

// ---------------------------------------------------------------------------
// fused gram kernel with norm-folded weights (unchanged)
// ---------------------------------------------------------------------------
__global__ __launch_bounds__(128) void gram_kernel(
    const float* __restrict__ Xt, const float* __restrict__ atT, const float* __restrict__ s1,
    const float* __restrict__ Xo, const float* __restrict__ atO, const float* __restrict__ s2,
    const float* __restrict__ rho_p, const float* __restrict__ nu_p, const float* __restrict__ g_p,
    float* __restrict__ KoxT, float* __restrict__ Kxx, double* __restrict__ Koo,
    double* __restrict__ Bc) {
    const int mode = blockIdx.z;
    const int it = blockIdx.x, jt = blockIdx.y;
    const float *X1, *AT1, *S1, *X2, *AT2, *S2;
    if (mode == 0) {
        if (jt > 2 * it + 1) return;
        X1 = Xo; AT1 = atO; S1 = s2; X2 = Xo; AT2 = atO; S2 = s2;
    } else if (mode == 1) {
        if (jt >= 32) return;
        X1 = Xo; AT1 = atO; S1 = s2; X2 = Xt; AT2 = atT; S2 = s1;
    } else {
        if (it >= 16 || jt >= 32 || jt < 2 * it) return;
        X1 = Xt; AT1 = atT; S1 = s1; X2 = Xt; AT2 = atT; S2 = s1;
    }
    const int i0 = it * 16, j0 = jt * 8;
    const int tid = threadIdx.x;
    const int il = tid >> 3, uc = tid & 7;
    const int i = i0 + il;

    __shared__ __align__(16) float X2s[8 * 192];
    __shared__ float A2s[8 * 24];
    __shared__ float S2s[8];
    {
        const float4* gx = (const float4*)(X2 + (size_t)j0 * 192);
        float4* lx = (float4*)X2s;
        for (int idx = tid; idx < 8 * 48; idx += 128) lx[idx] = gx[idx];
        for (int idx = tid; idx < 8 * 24; idx += 128) A2s[idx] = AT2[(size_t)j0 * 24 + idx];
        if (tid < 8) S2s[tid] = S2[j0 + tid];
    }
    __syncthreads();

    float x1r[3][8], at1r[3];
#pragma unroll
    for (int ss = 0; ss < 3; ++ss) {
        const float* p = X1 + ((size_t)i * P + uc * 3 + ss) * D;
#pragma unroll
        for (int d = 0; d < D; ++d) x1r[ss][d] = p[d];
        at1r[ss] = AT1[(size_t)i * P + uc * 3 + ss];
    }
    const float s1i = S1[i];
    const float rho = rho_p[0], nu = nu_p[0], g = g_p[0];

    for (int jj = 0; jj < 8; ++jj) {
        const float* xb = X2s + jj * 192;
        float e0 = 0.f, e1 = 0.f, e2 = 0.f;
#pragma unroll 4
        for (int v = 0; v < 24; ++v) {
            const float4 q0 = ((const float4*)(xb + v * 8))[0];
            const float4 q1 = ((const float4*)(xb + v * 8))[1];
            float x2r[8];
            x2r[0] = q0.x; x2r[1] = q0.y; x2r[2] = q0.z; x2r[3] = q0.w;
            x2r[4] = q1.x; x2r[5] = q1.y; x2r[6] = q1.z; x2r[7] = q1.w;
            const float w2 = A2s[jj * 24 + v];
            float d0 = 0.f, d1 = 0.f, d2 = 0.f;
#pragma unroll
            for (int dd = 0; dd < 8; ++dd) {
                d0 = fmaf(x1r[0][dd], x2r[dd], d0);
                d1 = fmaf(x1r[1][dd], x2r[dd], d1);
                d2 = fmaf(x1r[2][dd], x2r[dd], d2);
            }
            e0 = fmaf(w2, __expf(d0), e0);
            e1 = fmaf(w2, __expf(d1), e1);
            e2 = fmaf(w2, __expf(d2), e2);
        }
        float acc = at1r[0] * e0;
        acc = fmaf(at1r[1], e1, acc);
        acc = fmaf(at1r[2], e2, acc);
        acc += __shfl_xor(acc, 1, 8);
        acc += __shfl_xor(acc, 2, 8);
        acc += __shfl_xor(acc, 4, 8);
        if (uc == 0) {
            const int j = j0 + jj;
            float d2p = fmaxf(s1i + S2s[jj] - 2.f * acc, 0.f);
            float kv = __expf(-0.5f * d2p / rho);
            if (mode == 0) {
                if (j <= i) Koo[(size_t)i * 512 + j] = (double)(nu * (kv + ((i == j) ? g : 0.f)));
            } else if (mode == 1) {
                float val = nu * kv;
                KoxT[(size_t)j * 512 + i] = val;
                Bc[(size_t)j * 512 + i] = (double)val;
            } else {
                float val = nu * kv;
                if (j >= i) {
                    Kxx[(size_t)i * 256 + j] = val;
                    if (j > i) Kxx[(size_t)j * 256 + i] = val;
                }
            }
        }
    }
}

// ---------------------------------------------------------------------------
// Conflict-free 64x64 f64 tile engine (r12, unchanged).
// ---------------------------------------------------------------------------
__device__ __forceinline__ double2 ld2t(const double* T, int r, int m) {
    return *(const double2*)(T + r * 64 + 2 * ((m ^ (r >> 2)) & 31));
}
__device__ __forceinline__ void st2t(double* T, int r, int m, double x, double y) {
    double2 v; v.x = x; v.y = y;
    *(double2*)(T + r * 64 + 2 * ((m ^ (r >> 2)) & 31)) = v;
}

__device__ void stage_tile(double* T, const double* G, int ldg, int nrows) {
    const int tid = threadIdx.x;
#pragma unroll
    for (int e = 0; e < 8; ++e) {
        int idx = tid + 256 * e, r = idx >> 5, m = idx & 31;
        double x = 0.0, y = 0.0;
        if (r < nrows) {
            double2 v = *(const double2*)(G + (size_t)r * ldg + 2 * m);
            x = v.x; y = v.y;
        }
        st2t(T, r, m, x, y);
    }
}
__device__ void stage_tile_f(double* T, const float* G, int ldg) {
    const int tid = threadIdx.x;
#pragma unroll
    for (int e = 0; e < 8; ++e) {
        int idx = tid + 256 * e, r = idx >> 5, m = idx & 31;
        float2 v = *(const float2*)(G + (size_t)r * ldg + 2 * m);
        st2t(T, r, m, (double)v.x, (double)v.y);
    }
}

// acc[r][c] += sum_t At[4ty+r][t] * Bt[4tx+c][t]
__device__ __forceinline__ void mac4x4(const double* At, const double* Bt,
                                       double acc[4][4], int tx, int ty) {
#pragma unroll 4
    for (int m = 0; m < 32; ++m) {
        double2 a[4], b[4];
#pragma unroll
        for (int j = 0; j < 4; ++j) a[j] = ld2t(At, 4 * ty + j, m);
#pragma unroll
        for (int j = 0; j < 4; ++j) b[j] = ld2t(Bt, 4 * tx + j, m);
#pragma unroll
        for (int r = 0; r < 4; ++r)
#pragma unroll
            for (int c = 0; c < 4; ++c)
                acc[r][c] = fma(a[r].y, b[c].y, fma(a[r].x, b[c].x, acc[r][c]));
    }
}

__device__ void stt_tile(double* T, const double v[4][4], int tx, int ty) {
#pragma unroll
    for (int r = 0; r < 4; ++r)
#pragma unroll
        for (int mp = 0; mp < 2; ++mp)
            st2t(T, 4 * ty + r, 2 * tx + mp, v[r][2 * mp], v[r][2 * mp + 1]);
}

#define LO(i, j) ((i) * ((i) + 1) / 2 + (j))   // packed lower-tile index (i>=j)

// ---------------------------------------------------------------------------
// fast f64 reciprocal / rsqrt via HW estimate + Newton.
// ---------------------------------------------------------------------------
__device__ __forceinline__ double frcp(double d) {
    double r;
    asm("v_rcp_f64 %0, %1" : "=v"(r) : "v"(d));
    double e = fma(-d, r, 1.0); r = fma(r, e, r);
    e = fma(-d, r, 1.0); r = fma(r, e, r);
    return r;
}
__device__ __forceinline__ double frsq(double d) {
    double r;
    asm("v_rsq_f64 %0, %1" : "=v"(r) : "v"(d));
    double t = -0.5 * d * r; r = r * fma(t, r, 1.5);
    t = -0.5 * d * r; r = r * fma(t, r, 1.5);
    return r;
}

// ---------------------------------------------------------------------------
// factor64 v6 — runtime OUTER loop + unrolled INNER-16 batch (r16 post-mortem:
// v5's unroll-1 inner made each of 16 RMWs a separate ~150cy latency chain;
// batching the 16 independent LDS ops under one wait -> ~400cy/step).
// Code ~3KB (I-cache resident). Same math/layout as v5 (passed r16).
// Elimination: thread (r=tid&63, g=tid>>6) owns row r, cols [16g,16g+16).
// Inverse: column-per-lane (c=tid&63), row stripes rr=q+4j (compile-time).
// Writes X = inv(L_chol) to packed Wp/WTp tile p. All 256 threads enter.
// ---------------------------------------------------------------------------
__device__ void factor64v6(double* sA, double* sX, double* cb,
                           double* __restrict__ Wp, double* __restrict__ WTp,
                           int p) {
    const int tid = threadIdx.x;
    const int r = tid & 63, g = tid >> 6, c0 = 16 * g;
    double* myrow = sA + r * 65 + c0;
    // LDL elimination (lower triangle), one barrier per pivot; inner 16 batched
#pragma unroll 1
    for (int k = 0; k < 64; ++k) {
        double inv = frcp(sA[k * 65 + k]);
        double s = (r > k) ? sA[r * 65 + k] * inv : 0.0;
        double cv[16], nv[16];
#pragma unroll
        for (int j = 0; j < 16; ++j) cv[j] = sA[(c0 + j) * 65 + k];   // wave-broadcast
#pragma unroll
        for (int j = 0; j < 16; ++j) nv[j] = fma(-s, cv[j], myrow[j]);
#pragma unroll
        for (int j = 0; j < 16; ++j) {
            int c = c0 + j;
            if (c > k && c <= r) myrow[j] = nv[j];
        }
        __syncthreads();
    }
    // invd, rs; zero sX
    if (tid < 64) {
        double d = sA[tid * 65 + tid];
        cb[tid] = frcp(d);
        cb[64 + tid] = frsq(d);
    }
#pragma unroll 1
    for (int i = tid; i < 4160; i += 256) sX[i] = 0.0;
    __syncthreads();
    // scale lower to unit-lower Lu; set sX diag (batched)
    {
        double sc[16];
#pragma unroll
        for (int j = 0; j < 16; ++j) sc[j] = cb[c0 + j];
#pragma unroll
        for (int j = 0; j < 16; ++j)
            if (c0 + j < r) myrow[j] *= sc[j];
    }
    if (tid < 64) sX[tid * 65 + tid] = 1.0;
    __syncthreads();
    // inverse of Lu: column-parallel deferred GE, stripes rr = q + 4j
    {
        const int c = tid & 63, q = tid >> 6;
#pragma unroll 1
        for (int t = 0; t < 63; ++t) {
            double xt = sX[t * 65 + c];
            double lv[16], cur[16];
#pragma unroll
            for (int j = 0; j < 16; ++j) lv[j] = sA[(q + 4 * j) * 65 + t];   // broadcast
#pragma unroll
            for (int j = 0; j < 16; ++j) cur[j] = sX[(q + 4 * j) * 65 + c];
#pragma unroll
            for (int j = 0; j < 16; ++j) {
                int rr = q + 4 * j;
                if (rr > t) sX[rr * 65 + c] = fma(-lv[j], xt, cur[j]);
            }
            __syncthreads();
        }
        // X[r][c] = Yu[r][c] * rs_r; write packed Wp (row-major) + WTp
        const size_t off = (size_t)LO(p, p) * 4096;
#pragma unroll
        for (int j = 0; j < 16; ++j) {
            int rr = q + 4 * j;
            double xv = sX[rr * 65 + c] * cb[64 + rr];
            Wp[off + (size_t)rr * 64 + c] = xv;
            WTp[off + (size_t)c * 64 + rr] = xv;
        }
    }
}

// factor of panel 0 (standalone): stage lower triangle, run v6
__global__ __launch_bounds__(256) void factor0_kernel(const double* __restrict__ A,
                                                      double* __restrict__ Wp,
                                                      double* __restrict__ WTp) {
    __shared__ double smem[4160 + 4160 + 128];
    const int tid = threadIdx.x;
    for (int idx = tid; idx < 4096; idx += 256) {
        int r = idx >> 6, c = idx & 63;
        if (c <= r) smem[r * 65 + c] = A[(size_t)r * 512 + c];
    }
    __syncthreads();
    factor64v6(smem, smem + 4160, smem + 8320, Wp, WTp, 0);
}

// ---------------------------------------------------------------------------
// trailing-update tile for panel p; block (0,0) factors panel p+1 in place
// (embedded, r13-proven pattern) via factor64v6.
// ---------------------------------------------------------------------------
__device__ void upd_tile(double* smem, double* A, double* LL,
                         double* Wp, double* WTp, int p, int s, int tx, int ty) {
    double* T0 = smem;
    double* T1 = smem + 4096;
    double* T2 = smem + 8192;
    int bi = 0;
    while (s >= bi + 1) { s -= bi + 1; ++bi; }
    const int bj = s;
    const int I = p + 1 + bi, J = p + 1 + bj;
    const bool diag = (I == J);

    stage_tile(T0, A + (size_t)I * 64 * 512 + p * 64, 512, 64);
    if (!diag) stage_tile(T1, A + (size_t)J * 64 * 512 + p * 64, 512, 64);
    stage_tile(T2, Wp + (size_t)LO(p, p) * 4096, 64, 64);   // Dinv_p: T2[c][t]=X[c][t]
    __syncthreads();

    double lip[4][4] = {}, ljp[4][4] = {};
    mac4x4(T0, T2, lip, tx, ty);                             // L_Ip = A_Ip · X^T
    if (!diag) mac4x4(T1, T2, ljp, tx, ty);
    __syncthreads();
    stt_tile(T0, lip, tx, ty);
    if (!diag) stt_tile(T1, ljp, tx, ty);
    if (diag) {                                              // publish L tile (I,p)
#pragma unroll
        for (int r = 0; r < 4; ++r)
#pragma unroll
            for (int c = 0; c < 4; ++c)
                LL[(size_t)(I * 64 + 4 * ty + r) * 512 + p * 64 + 4 * tx + c] = lip[r][c];
    }
    __syncthreads();

    double acc[4][4] = {};
    mac4x4(T0, diag ? T0 : T1, acc, tx, ty);                 // L_Ip · L_Jp^T

    double* Aij = A + (size_t)I * 64 * 512 + (size_t)J * 64;
    if (bi == 0 && bj == 0) {
        // factor panel p+1 in place: write updated diag tile (lower) into sA
        __syncthreads();
#pragma unroll
        for (int r = 0; r < 4; ++r)
#pragma unroll
            for (int c = 0; c < 4; ++c) {
                int rr = 4 * ty + r, cc = 4 * tx + c;
                if (cc <= rr) smem[rr * 65 + cc] = Aij[(size_t)rr * 512 + cc] - acc[r][c];
            }
        __syncthreads();
        factor64v6(smem, smem + 4160, smem + 8320, Wp, WTp, p + 1);
    } else {
#pragma unroll
        for (int r = 0; r < 4; ++r)
#pragma unroll
            for (int c = 0; c < 4; ++c) {
                int rr = 4 * ty + r, cc = 4 * tx + c;
                if (!diag || cc <= rr)
                    Aij[(size_t)rr * 512 + cc] -= acc[r][c];
            }
    }
}

// W row-panel p tile J (J<p): X_pJ = -Dinv_p * sum_{K=J..p-1} L_pK * X_KJ
__device__ void wrow_tile(double* smem, const double* LL,
                          double* Wp, double* WTp, int p, int J, int tx, int ty) {
    double* T0 = smem;
    double* T1 = smem + 4096;
    double* T2 = smem + 8192;
    stage_tile(T2, Wp + (size_t)LO(p, p) * 4096, 64, 64);    // Dinv_p
    double S[4][4] = {};
    for (int K = J; K < p; ++K) {
        stage_tile(T0, LL + (size_t)(p * 64) * 512 + K * 64, 512, 64);   // L_pK rows
        stage_tile(T1, WTp + (size_t)LO(K, J) * 4096, 64, 64);           // T1[a][b]=X_KJ[b][a]
        __syncthreads();
        mac4x4(T0, T1, S, tx, ty);                           // S += L_pK · X_KJ
        __syncthreads();
    }
    // store S transposed into T0: T0[c'][t'] = S_glob[t'][c']
#pragma unroll
    for (int c = 0; c < 4; ++c)
#pragma unroll
        for (int rp = 0; rp < 2; ++rp)
            st2t(T0, 4 * tx + c, 2 * ty + rp, S[2 * rp][c], S[2 * rp + 1][c]);
    __syncthreads();
    double X[4][4] = {};
    mac4x4(T2, T0, X, tx, ty);                               // Dinv_p · S
    const size_t wo = (size_t)LO(p, J) * 4096;
#pragma unroll
    for (int r = 0; r < 4; ++r)
#pragma unroll
        for (int c = 0; c < 4; ++c) {
            Wp[wo + (size_t)(4 * ty + r) * 64 + 4 * tx + c] = -X[r][c];
            WTp[wo + (size_t)(4 * tx + c) * 64 + 4 * ty + r] = -X[r][c];
        }
}

// upd launch p: blocks [0,nupd) trailing tiles; [nupd, nupd+p) W row-panel p
__global__ __launch_bounds__(256) void upd_kernel(double* __restrict__ A,
                                                  double* __restrict__ LL,
                                                  double* __restrict__ Wp,
                                                  double* __restrict__ WTp,
                                                  int p) {
    __shared__ double smem[12288];
    const int tx = threadIdx.x & 15, ty = threadIdx.x >> 4;
    const int nupd = (7 - p) * (8 - p) / 2;
    if ((int)blockIdx.x < nupd)
        upd_tile(smem, A, LL, Wp, WTp, p, blockIdx.x, tx, ty);
    else
        wrow_tile(smem, LL, Wp, WTp, p, blockIdx.x - nupd, tx, ty);
}

__global__ __launch_bounds__(256) void wrow7_kernel(const double* __restrict__ LL,
                                                    double* __restrict__ Wp,
                                                    double* __restrict__ WTp) {
    __shared__ double smem[12288];
    const int tx = threadIdx.x & 15, ty = threadIdx.x >> 4;
    wrow_tile(smem, LL, Wp, WTp, 7, blockIdx.x, tx, ty);
}

// ---------------------------------------------------------------------------
// GEMMs: T = W*B, then Z = W^T*T. B,T,Z col-major [col][512].
// ---------------------------------------------------------------------------
__global__ __launch_bounds__(256) void gemm1_kernel(const double* __restrict__ Wp,
                                                    const double* __restrict__ Bc,
                                                    double* __restrict__ Tbuf) {
    __shared__ double smem[8192];
    const int blk = blockIdx.x;
    const int i = blk / 5, ct = blk % 5, c0 = ct * 64;
    const int nr = (257 - c0 < 64) ? (257 - c0) : 64;
    double* T0 = smem;
    double* T1 = smem + 4096;
    const int tx = threadIdx.x & 15, ty = threadIdx.x >> 4;
    double acc[4][4] = {};
    for (int j = 0; j <= i; ++j) {
        stage_tile(T0, Wp + (size_t)LO(i, j) * 4096, 64, 64);
        stage_tile(T1, Bc + (size_t)c0 * 512 + j * 64, 512, nr);
        __syncthreads();
        mac4x4(T0, T1, acc, tx, ty);
        __syncthreads();
    }
#pragma unroll
    for (int r = 0; r < 4; ++r)
#pragma unroll
        for (int c = 0; c < 4; ++c) {
            int cc = c0 + 4 * tx + c;
            if (cc < 257) Tbuf[(size_t)cc * 512 + i * 64 + 4 * ty + r] = acc[r][c];
        }
}

__global__ __launch_bounds__(256) void gemm2_kernel(const double* __restrict__ WTp,
                                                    const double* __restrict__ Tbuf,
                                                    double* __restrict__ Bc) {
    __shared__ double smem[8192];
    const int blk = blockIdx.x;
    const int i = blk / 5, ct = blk % 5, c0 = ct * 64;
    const int nr = (257 - c0 < 64) ? (257 - c0) : 64;
    double* T0 = smem;
    double* T1 = smem + 4096;
    const int tx = threadIdx.x & 15, ty = threadIdx.x >> 4;
    double acc[4][4] = {};
    for (int j = i; j < 8; ++j) {
        stage_tile(T0, WTp + (size_t)LO(j, i) * 4096, 64, 64);   // T0[a][t]=W[j64+t][i64+a]
        stage_tile(T1, Tbuf + (size_t)c0 * 512 + j * 64, 512, nr);
        __syncthreads();
        mac4x4(T0, T1, acc, tx, ty);
        __syncthreads();
    }
#pragma unroll
    for (int r = 0; r < 4; ++r)
#pragma unroll
        for (int c = 0; c < 4; ++c) {
            int cc = c0 + 4 * tx + c;
            if (cc < 257) Bc[(size_t)cc * 512 + i * 64 + 4 * ty + r] = acc[r][c];
        }
}

// column reductions over Z (col-major [257][512]); 4 cols per block
__global__ __launch_bounds__(256) void colreduce_kernel(const double* __restrict__ Z,
                                                        const float* __restrict__ ys,
                                                        const float* __restrict__ b_p,
                                                        float* __restrict__ out,
                                                        double* __restrict__ kbx,
                                                        double* __restrict__ Sp) {
    const int lane = threadIdx.x & 63, w = threadIdx.x >> 6;
    const int c = blockIdx.x * 4 + w;
    if (c >= 257) return;
    const double b = (double)b_p[0];
    double s0 = 0.0, s1 = 0.0;
#pragma unroll
    for (int t = 0; t < 8; ++t) {
        int n = lane + 64 * t;
        double zv = Z[(size_t)c * 512 + n];
        s0 += zv;
        s1 = fma(zv, (double)ys[n] - b, s1);
    }
#pragma unroll
    for (int off = 1; off < 64; off <<= 1) {
        s0 += __shfl_xor(s0, off, 64);
        s1 += __shfl_xor(s1, off, 64);
    }
    if (lane == 0) {
        if (c < 256) { out[c] = (float)(b + s1); kbx[c] = s0; }
        else Sp[0] = s0;
    }
}

// cov[i][j] = Kxx[i][j] - sum_n Z[i][n]*Kox[n][j] + (1-kbx[i])(1-kbx[j])/S
__global__ __launch_bounds__(256) void cov_kernel(const double* __restrict__ Z,
                                                  const float* __restrict__ KoxT,
                                                  const float* __restrict__ Kxx,
                                                  const double* __restrict__ kbx,
                                                  const double* __restrict__ Sp,
                                                  float* __restrict__ out) {
    __shared__ double smem[8192];
    const int bi = blockIdx.x >> 2, bj = blockIdx.x & 3;
    double* T0 = smem;
    double* T1 = smem + 4096;
    const int tx = threadIdx.x & 15, ty = threadIdx.x >> 4;
    double acc[4][4] = {};
    for (int kt = 0; kt < 8; ++kt) {
        stage_tile(T0, Z + (size_t)(bi * 64) * 512 + kt * 64, 512, 64);
        stage_tile_f(T1, KoxT + (size_t)(bj * 64) * 512 + kt * 64, 512);
        __syncthreads();
        mac4x4(T0, T1, acc, tx, ty);
        __syncthreads();
    }
    const double S = Sp[0];
#pragma unroll
    for (int r = 0; r < 4; ++r) {
        int i = bi * 64 + 4 * ty + r;
        double ki = 1.0 - kbx[i];
#pragma unroll
        for (int c = 0; c < 4; ++c) {
            int j = bj * 64 + 4 * tx + c;
            double corr = ki * (1.0 - kbx[j]) / S;
            out[(size_t)(1 + i) * 256 + j] =
                (float)((double)Kxx[(size_t)i * 256 + j] - acc[r][c] + corr);
        }
    }
}

// ---------------------------------------------------------------------------
extern "C" void kernel_launch(void* const* d_in, const int* in_sizes, int n_in,
                              void* d_out, int out_size, void* d_ws, size_t ws_size,
                              hipStream_t stream) {
    const float* X_test = (const float*)d_in[0];
    const float* A_test = (const float*)d_in[1];
    const float* X_obs  = (const float*)d_in[2];
    const float* A_obs  = (const float*)d_in[3];
    const float* ys     = (const float*)d_in[4];
    const float* rho_p  = (const float*)d_in[5];
    const float* g_p    = (const float*)d_in[6];
    const float* nu_p   = (const float*)d_in[7];
    const float* b_p    = (const float*)d_in[8];
    float* out = (float*)d_out;
    char* ws = (char*)d_ws;

    double* Koo  = (double*)(ws + 0);         // 2,097,152 (A; Tbuf alias post-chol)
    double* LL   = (double*)(ws + 2097152);   // 2,097,152 (L row-major; atT/atO overlay pre-chol)
    double* Bc   = (double*)(ws + 4194304);   // 1,052,672 (RHS -> Z)
    float*  KoxT = (float*) (ws + 5246976);   // 524,288
    float*  Kxx  = (float*) (ws + 5771264);   // 262,144
    float*  s1v  = (float*) (ws + 6033408);   // 1,024
    float*  s2v  = (float*) (ws + 6034432);   // 2,048
    double* kbx  = (double*)(ws + 6036480);   // 2,048
    double* Sp   = (double*)(ws + 6038528);   // 1,024 (pad)
    double* Wp   = (double*)(ws + 6039552);   // 36*32768 = 1,179,648
    double* WTp  = (double*)(ws + 7219200);   // 1,179,648 (end 8,398,848)
    double* Tbuf = Koo;                       // aliases dead A after chol
    float*  atT  = (float*)(ws + 2097152);
    float*  atO  = (float*)(ws + 2097152 + 24576);

    self_kernel<<<M + N + 1, 64, 0, stream>>>(X_test, A_test, X_obs, A_obs,
                                              s1v, s2v, atT, atO, Bc);

    gram_kernel<<<dim3(32, 64, 3), 128, 0, stream>>>(X_test, atT, s1v,
                                                     X_obs, atO, s2v,
                                                     rho_p, nu_p, g_p,
                                                     KoxT, Kxx, Koo, Bc);

    factor0_kernel<<<1, 256, 0, stream>>>(Koo, Wp, WTp);
    for (int p = 0; p < 7; ++p) {
        int nb = (7 - p) * (8 - p) / 2 + p;   // trailing tiles + W row-panel p
        upd_kernel<<<nb, 256, 0, stream>>>(Koo, LL, Wp, WTp, p);
    }
    wrow7_kernel<<<7, 256, 0, stream>>>(LL, Wp, WTp);

    gemm1_kernel<<<40, 256, 0, stream>>>(Wp, Bc, Tbuf);
    gemm2_kernel<<<40, 256, 0, stream>>>(WTp, Tbuf, Bc);
    colreduce_kernel<<<65, 256, 0, stream>>>(Bc, ys, b_p, out, kbx, Sp);
    cov_kernel<<<16, 256, 0, stream>>>(Bc, KoxT, Kxx, kbx, Sp, out);
}

// Round 18
// 833.951 us; speedup vs baseline: 2.9968x; 1.5122x over previous
//
#include <hip/hip_runtime.h>
#include <cmath>

// Problem constants
#define M 256
#define N 512
#define P 24
#define D 8

// ---------------------------------------------------------------------------
// self terms + folded weights at[i,u] = A[i,u]*exp(-0.5*||x_iu||^2).
// Block M+N writes the ones-column of Bc.
// ---------------------------------------------------------------------------
__global__ __launch_bounds__(64) void self_kernel(const float* __restrict__ X_test,
                                                  const float* __restrict__ A_test,
                                                  const float* __restrict__ X_obs,
                                                  const float* __restrict__ A_obs,
                                                  float* __restrict__ s1,
                                                  float* __restrict__ s2,
                                                  float* __restrict__ atT,
                                                  float* __restrict__ atO,
                                                  double* __restrict__ Bc) {
    const int bid = blockIdx.x;
    const int lane = threadIdx.x;
    if (bid == M + N) {  // ones column (col 256 of Bc, col-major [257][512])
#pragma unroll
        for (int t = 0; t < 8; ++t) Bc[(size_t)256 * 512 + 64 * t + lane] = 1.0;
        return;
    }
    const float* X; const float* A; float* s; float* at; int i;
    if (bid < M) { X = X_test; A = A_test; s = s1; at = atT; i = bid; }
    else         { X = X_obs;  A = A_obs;  s = s2; at = atO; i = bid - M; }
    const float* Xi = X + (size_t)i * P * D;
    const float* Ai = A + (size_t)i * P;
    float acc = 0.f;
#pragma unroll
    for (int t = 0; t < 9; ++t) {
        int idx = lane + 64 * t;          // 0..575
        int u = idx / 24;
        int v = idx - u * 24;
        const float* xu = Xi + u * D;
        const float* xv = Xi + v * D;
        float d2 = 0.f;
#pragma unroll
        for (int d = 0; d < D; ++d) { float df = xu[d] - xv[d]; d2 = fmaf(df, df, d2); }
        acc = fmaf(Ai[u] * Ai[v], __expf(-0.5f * d2), acc);
    }
#pragma unroll
    for (int off = 1; off < 64; off <<= 1) acc += __shfl_xor(acc, off, 64);
    if (lane == 0) s[i] = acc;
    if (lane < 24) {
        const float* xp = Xi + lane * D;
        float q = 0.f;
#pragma unroll
        for (int d = 0; d < D; ++d) q = fmaf(xp[d], xp[d], q);
        at[(size_t)i * P + lane] = Ai[lane] * __expf(-0.5f * q);
    }
}

// ---------------------------------------------------------------------------
// fused gram kernel with norm-folded weights (unchanged)
// ---------------------------------------------------------------------------
__global__ __launch_bounds__(128) void gram_kernel(
    const float* __restrict__ Xt, const float* __restrict__ atT, const float* __restrict__ s1,
    const float* __restrict__ Xo, const float* __restrict__ atO, const float* __restrict__ s2,
    const float* __restrict__ rho_p, const float* __restrict__ nu_p, const float* __restrict__ g_p,
    float* __restrict__ KoxT, float* __restrict__ Kxx, double* __restrict__ Koo,
    double* __restrict__ Bc) {
    const int mode = blockIdx.z;
    const int it = blockIdx.x, jt = blockIdx.y;
    const float *X1, *AT1, *S1, *X2, *AT2, *S2;
    if (mode == 0) {
        if (jt > 2 * it + 1) return;
        X1 = Xo; AT1 = atO; S1 = s2; X2 = Xo; AT2 = atO; S2 = s2;
    } else if (mode == 1) {
        if (jt >= 32) return;
        X1 = Xo; AT1 = atO; S1 = s2; X2 = Xt; AT2 = atT; S2 = s1;
    } else {
        if (it >= 16 || jt >= 32 || jt < 2 * it) return;
        X1 = Xt; AT1 = atT; S1 = s1; X2 = Xt; AT2 = atT; S2 = s1;
    }
    const int i0 = it * 16, j0 = jt * 8;
    const int tid = threadIdx.x;
    const int il = tid >> 3, uc = tid & 7;
    const int i = i0 + il;

    __shared__ __align__(16) float X2s[8 * 192];
    __shared__ float A2s[8 * 24];
    __shared__ float S2s[8];
    {
        const float4* gx = (const float4*)(X2 + (size_t)j0 * 192);
        float4* lx = (float4*)X2s;
        for (int idx = tid; idx < 8 * 48; idx += 128) lx[idx] = gx[idx];
        for (int idx = tid; idx < 8 * 24; idx += 128) A2s[idx] = AT2[(size_t)j0 * 24 + idx];
        if (tid < 8) S2s[tid] = S2[j0 + tid];
    }
    __syncthreads();

    float x1r[3][8], at1r[3];
#pragma unroll
    for (int ss = 0; ss < 3; ++ss) {
        const float* p = X1 + ((size_t)i * P + uc * 3 + ss) * D;
#pragma unroll
        for (int d = 0; d < D; ++d) x1r[ss][d] = p[d];
        at1r[ss] = AT1[(size_t)i * P + uc * 3 + ss];
    }
    const float s1i = S1[i];
    const float rho = rho_p[0], nu = nu_p[0], g = g_p[0];

    for (int jj = 0; jj < 8; ++jj) {
        const float* xb = X2s + jj * 192;
        float e0 = 0.f, e1 = 0.f, e2 = 0.f;
#pragma unroll 4
        for (int v = 0; v < 24; ++v) {
            const float4 q0 = ((const float4*)(xb + v * 8))[0];
            const float4 q1 = ((const float4*)(xb + v * 8))[1];
            float x2r[8];
            x2r[0] = q0.x; x2r[1] = q0.y; x2r[2] = q0.z; x2r[3] = q0.w;
            x2r[4] = q1.x; x2r[5] = q1.y; x2r[6] = q1.z; x2r[7] = q1.w;
            const float w2 = A2s[jj * 24 + v];
            float d0 = 0.f, d1 = 0.f, d2 = 0.f;
#pragma unroll
            for (int dd = 0; dd < 8; ++dd) {
                d0 = fmaf(x1r[0][dd], x2r[dd], d0);
                d1 = fmaf(x1r[1][dd], x2r[dd], d1);
                d2 = fmaf(x1r[2][dd], x2r[dd], d2);
            }
            e0 = fmaf(w2, __expf(d0), e0);
            e1 = fmaf(w2, __expf(d1), e1);
            e2 = fmaf(w2, __expf(d2), e2);
        }
        float acc = at1r[0] * e0;
        acc = fmaf(at1r[1], e1, acc);
        acc = fmaf(at1r[2], e2, acc);
        acc += __shfl_xor(acc, 1, 8);
        acc += __shfl_xor(acc, 2, 8);
        acc += __shfl_xor(acc, 4, 8);
        if (uc == 0) {
            const int j = j0 + jj;
            float d2p = fmaxf(s1i + S2s[jj] - 2.f * acc, 0.f);
            float kv = __expf(-0.5f * d2p / rho);
            if (mode == 0) {
                if (j <= i) Koo[(size_t)i * 512 + j] = (double)(nu * (kv + ((i == j) ? g : 0.f)));
            } else if (mode == 1) {
                float val = nu * kv;
                KoxT[(size_t)j * 512 + i] = val;
                Bc[(size_t)j * 512 + i] = (double)val;
            } else {
                float val = nu * kv;
                if (j >= i) {
                    Kxx[(size_t)i * 256 + j] = val;
                    if (j > i) Kxx[(size_t)j * 256 + i] = val;
                }
            }
        }
    }
}

// ---------------------------------------------------------------------------
// Conflict-free 64x64 f64 tile engine (r12, unchanged).
// ---------------------------------------------------------------------------
__device__ __forceinline__ double2 ld2t(const double* T, int r, int m) {
    return *(const double2*)(T + r * 64 + 2 * ((m ^ (r >> 2)) & 31));
}
__device__ __forceinline__ void st2t(double* T, int r, int m, double x, double y) {
    double2 v; v.x = x; v.y = y;
    *(double2*)(T + r * 64 + 2 * ((m ^ (r >> 2)) & 31)) = v;
}

__device__ void stage_tile(double* T, const double* G, int ldg, int nrows) {
    const int tid = threadIdx.x;
#pragma unroll
    for (int e = 0; e < 8; ++e) {
        int idx = tid + 256 * e, r = idx >> 5, m = idx & 31;
        double x = 0.0, y = 0.0;
        if (r < nrows) {
            double2 v = *(const double2*)(G + (size_t)r * ldg + 2 * m);
            x = v.x; y = v.y;
        }
        st2t(T, r, m, x, y);
    }
}
__device__ void stage_tile_f(double* T, const float* G, int ldg) {
    const int tid = threadIdx.x;
#pragma unroll
    for (int e = 0; e < 8; ++e) {
        int idx = tid + 256 * e, r = idx >> 5, m = idx & 31;
        float2 v = *(const float2*)(G + (size_t)r * ldg + 2 * m);
        st2t(T, r, m, (double)v.x, (double)v.y);
    }
}

// acc[r][c] += sum_t At[4ty+r][t] * Bt[4tx+c][t]
__device__ __forceinline__ void mac4x4(const double* At, const double* Bt,
                                       double acc[4][4], int tx, int ty) {
#pragma unroll 4
    for (int m = 0; m < 32; ++m) {
        double2 a[4], b[4];
#pragma unroll
        for (int j = 0; j < 4; ++j) a[j] = ld2t(At, 4 * ty + j, m);
#pragma unroll
        for (int j = 0; j < 4; ++j) b[j] = ld2t(Bt, 4 * tx + j, m);
#pragma unroll
        for (int r = 0; r < 4; ++r)
#pragma unroll
            for (int c = 0; c < 4; ++c)
                acc[r][c] = fma(a[r].y, b[c].y, fma(a[r].x, b[c].x, acc[r][c]));
    }
}

__device__ void stt_tile(double* T, const double v[4][4], int tx, int ty) {
#pragma unroll
    for (int r = 0; r < 4; ++r)
#pragma unroll
        for (int mp = 0; mp < 2; ++mp)
            st2t(T, 4 * ty + r, 2 * tx + mp, v[r][2 * mp], v[r][2 * mp + 1]);
}

#define LO(i, j) ((i) * ((i) + 1) / 2 + (j))   // packed lower-tile index (i>=j)

// ---------------------------------------------------------------------------
// fast f64 reciprocal / rsqrt via HW estimate + Newton.
// ---------------------------------------------------------------------------
__device__ __forceinline__ double frcp(double d) {
    double r;
    asm("v_rcp_f64 %0, %1" : "=v"(r) : "v"(d));
    double e = fma(-d, r, 1.0); r = fma(r, e, r);
    e = fma(-d, r, 1.0); r = fma(r, e, r);
    return r;
}
__device__ __forceinline__ double frsq(double d) {
    double r;
    asm("v_rsq_f64 %0, %1" : "=v"(r) : "v"(d));
    double t = -0.5 * d * r; r = r * fma(t, r, 1.5);
    t = -0.5 * d * r; r = r * fma(t, r, 1.5);
    return r;
}

// ---------------------------------------------------------------------------
// factor64 v7 — hierarchical: 8x8 register sub-factors (wave0, shfl-only
// dependent chain) + parallel panel/rank-8 updates + 7-level blocked inverse.
// ~40 barriers total vs v6's 127; serial math entirely in registers.
// sA [64][65] lower-valid. sX [64][65] scratch/output. aux: inv8s[512]+Stmp[512].
// Writes X = inv(L_chol) to packed Wp/WTp tile p. All 256 threads enter.
// ---------------------------------------------------------------------------
__device__ void factor64v7(double* sA, double* sX, double* aux,
                           double* __restrict__ Wp, double* __restrict__ WTp,
                           int p) {
    const int tid = threadIdx.x;
    double* inv8s = aux;          // [8][64]: inv(L8) per sub-block
    double* Stmp  = aux + 512;    // [7][64]: per-level partial sums

    // ---- Phase A: blocked Cholesky with 8x8 register sub-factors ----
#pragma unroll 1
    for (int kb = 0; kb < 8; ++kb) {
        const int k0 = 8 * kb;
        if (tid < 64) {
            const int i = tid >> 3, j = tid & 7;
            double v = (j <= i) ? sA[(k0 + i) * 65 + k0 + j]
                                : sA[(k0 + j) * 65 + k0 + i];
            // in-register 8x8 Cholesky (shfl broadcasts, no LDS)
#pragma unroll
            for (int t = 0; t < 8; ++t) {
                double d = __shfl(v, 9 * t, 64);
                double rs = frsq(d);
                if (j == t && i >= t) v *= rs;
                double lit = __shfl(v, 8 * i + t, 64);
                double ljt = __shfl(v, 8 * j + t, 64);
                if (i > t && j > t && j <= i) v = fma(-lit, ljt, v);
            }
            if (j <= i) sA[(k0 + i) * 65 + k0 + j] = v;
            // in-register inv(L8): column-oriented forward elimination on [L|I]
            double y = (i == j) ? 1.0 : 0.0;
#pragma unroll
            for (int t = 0; t < 8; ++t) {
                double ltt = __shfl(v, 9 * t, 64);
                double rinv = frcp(ltt);
                if (i == t) y *= rinv;
                double ytj = __shfl(y, 8 * t + j, 64);
                double lit = __shfl(v, 8 * i + t, 64);
                if (i > t) y = fma(-lit, ytj, y);
            }
            inv8s[kb * 64 + tid] = y;
        }
        __syncthreads();
        const int nt = 56 - k0;                 // trailing rows
        if (kb < 7 && tid < nt) {
            // panel: L[r][k0+j] = sum_{t<=j} A[r][k0+t] * inv8[j][t]
            const int r = k0 + 8 + tid;
            double a[8], o[8];
#pragma unroll
            for (int t = 0; t < 8; ++t) a[t] = sA[r * 65 + k0 + t];
#pragma unroll
            for (int j2 = 0; j2 < 8; ++j2) {
                double s = 0.0;
#pragma unroll
                for (int t = 0; t < 8; ++t)
                    if (t <= j2) s = fma(a[t], inv8s[kb * 64 + 8 * j2 + t], s);
                o[j2] = s;
            }
#pragma unroll
            for (int j2 = 0; j2 < 8; ++j2) sA[r * 65 + k0 + j2] = o[j2];
        }
        __syncthreads();
        if (kb < 7) {
            // rank-8 trailing update (lower incl next diag block)
            const int cnt = nt * (nt + 1) / 2;
#pragma unroll 1
            for (int it2 = tid; it2 < cnt; it2 += 256) {
                int ii = 0, s2 = it2;
                while (s2 >= ii + 1) { s2 -= ii + 1; ++ii; }
                const int gi = k0 + 8 + ii, gj = k0 + 8 + s2;
                double acc = 0.0;
#pragma unroll
                for (int t = 0; t < 8; ++t)
                    acc = fma(sA[gi * 65 + k0 + t], sA[gj * 65 + k0 + t], acc);
                sA[gi * 65 + gj] -= acc;
            }
        }
        __syncthreads();
    }

    // ---- Phase B: X = inv(L64) assembled from 8x8 blocks ----
#pragma unroll 1
    for (int idx2 = tid; idx2 < 4160; idx2 += 256) sX[idx2] = 0.0;
    __syncthreads();
#pragma unroll 1
    for (int it2 = tid; it2 < 512; it2 += 256) {
        int I = it2 >> 6, ij = it2 & 63, i = ij >> 3, j = ij & 7;
        if (j <= i) sX[(8 * I + i) * 65 + 8 * I + j] = inv8s[it2];
    }
    __syncthreads();
#pragma unroll 1
    for (int d = 1; d < 8; ++d) {
        const int npairs = 8 - d;
#pragma unroll 1
        for (int it2 = tid; it2 < npairs * 64; it2 += 256) {
            int pr = it2 >> 6, ij = it2 & 63, i = ij >> 3, j = ij & 7;
            int J = pr, I = pr + d;
            double s = 0.0;
#pragma unroll 1
            for (int K = J; K < I; ++K) {
#pragma unroll
                for (int t = 0; t < 8; ++t)
                    s = fma(sA[(8 * I + i) * 65 + 8 * K + t],
                            sX[(8 * K + t) * 65 + 8 * J + j], s);
            }
            Stmp[it2] = s;
        }
        __syncthreads();
#pragma unroll 1
        for (int it2 = tid; it2 < npairs * 64; it2 += 256) {
            int pr = it2 >> 6, ij = it2 & 63, i = ij >> 3, j = ij & 7;
            int J = pr, I = pr + d;
            double s = 0.0;
#pragma unroll
            for (int t = 0; t < 8; ++t)
                s = fma(inv8s[I * 64 + 8 * i + t], Stmp[pr * 64 + 8 * t + j], s);
            sX[(8 * I + i) * 65 + 8 * J + j] = -s;
        }
        __syncthreads();
    }
    // write packed outputs (upper = zeros from init)
    const size_t off = (size_t)LO(p, p) * 4096;
#pragma unroll 1
    for (int idx2 = tid; idx2 < 4096; idx2 += 256) {
        int r = idx2 >> 6, c = idx2 & 63;
        double xv = sX[r * 65 + c];
        Wp[off + idx2] = xv;
        WTp[off + (size_t)c * 64 + r] = xv;
    }
    __syncthreads();
}

// factor of panel 0 (standalone): stage lower triangle, run v7
__global__ __launch_bounds__(256) void factor0_kernel(const double* __restrict__ A,
                                                      double* __restrict__ Wp,
                                                      double* __restrict__ WTp) {
    __shared__ double smem[9344];
    const int tid = threadIdx.x;
    for (int idx = tid; idx < 4096; idx += 256) {
        int r = idx >> 6, c = idx & 63;
        if (c <= r) smem[r * 65 + c] = A[(size_t)r * 512 + c];
    }
    __syncthreads();
    factor64v7(smem, smem + 4160, smem + 8320, Wp, WTp, 0);
}

// ---------------------------------------------------------------------------
// trailing-update tile for panel p; block (0,0) factors panel p+1 in place
// (embedded) via factor64v7.
// ---------------------------------------------------------------------------
__device__ void upd_tile(double* smem, double* A, double* LL,
                         double* Wp, double* WTp, int p, int s, int tx, int ty) {
    double* T0 = smem;
    double* T1 = smem + 4096;
    double* T2 = smem + 8192;
    int bi = 0;
    while (s >= bi + 1) { s -= bi + 1; ++bi; }
    const int bj = s;
    const int I = p + 1 + bi, J = p + 1 + bj;
    const bool diag = (I == J);

    stage_tile(T0, A + (size_t)I * 64 * 512 + p * 64, 512, 64);
    if (!diag) stage_tile(T1, A + (size_t)J * 64 * 512 + p * 64, 512, 64);
    stage_tile(T2, Wp + (size_t)LO(p, p) * 4096, 64, 64);   // Dinv_p: T2[c][t]=X[c][t]
    __syncthreads();

    double lip[4][4] = {}, ljp[4][4] = {};
    mac4x4(T0, T2, lip, tx, ty);                             // L_Ip = A_Ip · X^T
    if (!diag) mac4x4(T1, T2, ljp, tx, ty);
    __syncthreads();
    stt_tile(T0, lip, tx, ty);
    if (!diag) stt_tile(T1, ljp, tx, ty);
    if (diag) {                                              // publish L tile (I,p)
#pragma unroll
        for (int r = 0; r < 4; ++r)
#pragma unroll
            for (int c = 0; c < 4; ++c)
                LL[(size_t)(I * 64 + 4 * ty + r) * 512 + p * 64 + 4 * tx + c] = lip[r][c];
    }
    __syncthreads();

    double acc[4][4] = {};
    mac4x4(T0, diag ? T0 : T1, acc, tx, ty);                 // L_Ip · L_Jp^T

    double* Aij = A + (size_t)I * 64 * 512 + (size_t)J * 64;
    if (bi == 0 && bj == 0) {
        // factor panel p+1 in place: write updated diag tile (lower) into sA
        __syncthreads();
#pragma unroll
        for (int r = 0; r < 4; ++r)
#pragma unroll
            for (int c = 0; c < 4; ++c) {
                int rr = 4 * ty + r, cc = 4 * tx + c;
                if (cc <= rr) smem[rr * 65 + cc] = Aij[(size_t)rr * 512 + cc] - acc[r][c];
            }
        __syncthreads();
        factor64v7(smem, smem + 4160, smem + 8320, Wp, WTp, p + 1);
    } else {
#pragma unroll
        for (int r = 0; r < 4; ++r)
#pragma unroll
            for (int c = 0; c < 4; ++c) {
                int rr = 4 * ty + r, cc = 4 * tx + c;
                if (!diag || cc <= rr)
                    Aij[(size_t)rr * 512 + cc] -= acc[r][c];
            }
    }
}

// W row-panel p tile J (J<p): X_pJ = -Dinv_p * sum_{K=J..p-1} L_pK * X_KJ
__device__ void wrow_tile(double* smem, const double* LL,
                          double* Wp, double* WTp, int p, int J, int tx, int ty) {
    double* T0 = smem;
    double* T1 = smem + 4096;
    double* T2 = smem + 8192;
    stage_tile(T2, Wp + (size_t)LO(p, p) * 4096, 64, 64);    // Dinv_p
    double S[4][4] = {};
    for (int K = J; K < p; ++K) {
        stage_tile(T0, LL + (size_t)(p * 64) * 512 + K * 64, 512, 64);   // L_pK rows
        stage_tile(T1, WTp + (size_t)LO(K, J) * 4096, 64, 64);           // T1[a][b]=X_KJ[b][a]
        __syncthreads();
        mac4x4(T0, T1, S, tx, ty);                           // S += L_pK · X_KJ
        __syncthreads();
    }
    // store S transposed into T0: T0[c'][t'] = S_glob[t'][c']
#pragma unroll
    for (int c = 0; c < 4; ++c)
#pragma unroll
        for (int rp = 0; rp < 2; ++rp)
            st2t(T0, 4 * tx + c, 2 * ty + rp, S[2 * rp][c], S[2 * rp + 1][c]);
    __syncthreads();
    double X[4][4] = {};
    mac4x4(T2, T0, X, tx, ty);                               // Dinv_p · S
    const size_t wo = (size_t)LO(p, J) * 4096;
#pragma unroll
    for (int r = 0; r < 4; ++r)
#pragma unroll
        for (int c = 0; c < 4; ++c) {
            Wp[wo + (size_t)(4 * ty + r) * 64 + 4 * tx + c] = -X[r][c];
            WTp[wo + (size_t)(4 * tx + c) * 64 + 4 * ty + r] = -X[r][c];
        }
}

// upd launch p: blocks [0,nupd) trailing tiles; [nupd, nupd+p) W row-panel p
__global__ __launch_bounds__(256) void upd_kernel(double* __restrict__ A,
                                                  double* __restrict__ LL,
                                                  double* __restrict__ Wp,
                                                  double* __restrict__ WTp,
                                                  int p) {
    __shared__ double smem[12288];
    const int tx = threadIdx.x & 15, ty = threadIdx.x >> 4;
    const int nupd = (7 - p) * (8 - p) / 2;
    if ((int)blockIdx.x < nupd)
        upd_tile(smem, A, LL, Wp, WTp, p, blockIdx.x, tx, ty);
    else
        wrow_tile(smem, LL, Wp, WTp, p, blockIdx.x - nupd, tx, ty);
}

__global__ __launch_bounds__(256) void wrow7_kernel(const double* __restrict__ LL,
                                                    double* __restrict__ Wp,
                                                    double* __restrict__ WTp) {
    __shared__ double smem[12288];
    const int tx = threadIdx.x & 15, ty = threadIdx.x >> 4;
    wrow_tile(smem, LL, Wp, WTp, 7, blockIdx.x, tx, ty);
}

// ---------------------------------------------------------------------------
// GEMMs: T = W*B, then Z = W^T*T. B,T,Z col-major [col][512].
// ---------------------------------------------------------------------------
__global__ __launch_bounds__(256) void gemm1_kernel(const double* __restrict__ Wp,
                                                    const double* __restrict__ Bc,
                                                    double* __restrict__ Tbuf) {
    __shared__ double smem[8192];
    const int blk = blockIdx.x;
    const int i = blk / 5, ct = blk % 5, c0 = ct * 64;
    const int nr = (257 - c0 < 64) ? (257 - c0) : 64;
    double* T0 = smem;
    double* T1 = smem + 4096;
    const int tx = threadIdx.x & 15, ty = threadIdx.x >> 4;
    double acc[4][4] = {};
    for (int j = 0; j <= i; ++j) {
        stage_tile(T0, Wp + (size_t)LO(i, j) * 4096, 64, 64);
        stage_tile(T1, Bc + (size_t)c0 * 512 + j * 64, 512, nr);
        __syncthreads();
        mac4x4(T0, T1, acc, tx, ty);
        __syncthreads();
    }
#pragma unroll
    for (int r = 0; r < 4; ++r)
#pragma unroll
        for (int c = 0; c < 4; ++c) {
            int cc = c0 + 4 * tx + c;
            if (cc < 257) Tbuf[(size_t)cc * 512 + i * 64 + 4 * ty + r] = acc[r][c];
        }
}

__global__ __launch_bounds__(256) void gemm2_kernel(const double* __restrict__ WTp,
                                                    const double* __restrict__ Tbuf,
                                                    double* __restrict__ Bc) {
    __shared__ double smem[8192];
    const int blk = blockIdx.x;
    const int i = blk / 5, ct = blk % 5, c0 = ct * 64;
    const int nr = (257 - c0 < 64) ? (257 - c0) : 64;
    double* T0 = smem;
    double* T1 = smem + 4096;
    const int tx = threadIdx.x & 15, ty = threadIdx.x >> 4;
    double acc[4][4] = {};
    for (int j = i; j < 8; ++j) {
        stage_tile(T0, WTp + (size_t)LO(j, i) * 4096, 64, 64);   // T0[a][t]=W[j64+t][i64+a]
        stage_tile(T1, Tbuf + (size_t)c0 * 512 + j * 64, 512, nr);
        __syncthreads();
        mac4x4(T0, T1, acc, tx, ty);
        __syncthreads();
    }
#pragma unroll
    for (int r = 0; r < 4; ++r)
#pragma unroll
        for (int c = 0; c < 4; ++c) {
            int cc = c0 + 4 * tx + c;
            if (cc < 257) Bc[(size_t)cc * 512 + i * 64 + 4 * ty + r] = acc[r][c];
        }
}

// column reductions over Z (col-major [257][512]); 4 cols per block
__global__ __launch_bounds__(256) void colreduce_kernel(const double* __restrict__ Z,
                                                        const float* __restrict__ ys,
                                                        const float* __restrict__ b_p,
                                                        float* __restrict__ out,
                                                        double* __restrict__ kbx,
                                                        double* __restrict__ Sp) {
    const int lane = threadIdx.x & 63, w = threadIdx.x >> 6;
    const int c = blockIdx.x * 4 + w;
    if (c >= 257) return;
    const double b = (double)b_p[0];
    double s0 = 0.0, s1 = 0.0;
#pragma unroll
    for (int t = 0; t < 8; ++t) {
        int n = lane + 64 * t;
        double zv = Z[(size_t)c * 512 + n];
        s0 += zv;
        s1 = fma(zv, (double)ys[n] - b, s1);
    }
#pragma unroll
    for (int off = 1; off < 64; off <<= 1) {
        s0 += __shfl_xor(s0, off, 64);
        s1 += __shfl_xor(s1, off, 64);
    }
    if (lane == 0) {
        if (c < 256) { out[c] = (float)(b + s1); kbx[c] = s0; }
        else Sp[0] = s0;
    }
}

// cov[i][j] = Kxx[i][j] - sum_n Z[i][n]*Kox[n][j] + (1-kbx[i])(1-kbx[j])/S
__global__ __launch_bounds__(256) void cov_kernel(const double* __restrict__ Z,
                                                  const float* __restrict__ KoxT,
                                                  const float* __restrict__ Kxx,
                                                  const double* __restrict__ kbx,
                                                  const double* __restrict__ Sp,
                                                  float* __restrict__ out) {
    __shared__ double smem[8192];
    const int bi = blockIdx.x >> 2, bj = blockIdx.x & 3;
    double* T0 = smem;
    double* T1 = smem + 4096;
    const int tx = threadIdx.x & 15, ty = threadIdx.x >> 4;
    double acc[4][4] = {};
    for (int kt = 0; kt < 8; ++kt) {
        stage_tile(T0, Z + (size_t)(bi * 64) * 512 + kt * 64, 512, 64);
        stage_tile_f(T1, KoxT + (size_t)(bj * 64) * 512 + kt * 64, 512);
        __syncthreads();
        mac4x4(T0, T1, acc, tx, ty);
        __syncthreads();
    }
    const double S = Sp[0];
#pragma unroll
    for (int r = 0; r < 4; ++r) {
        int i = bi * 64 + 4 * ty + r;
        double ki = 1.0 - kbx[i];
#pragma unroll
        for (int c = 0; c < 4; ++c) {
            int j = bj * 64 + 4 * tx + c;
            double corr = ki * (1.0 - kbx[j]) / S;
            out[(size_t)(1 + i) * 256 + j] =
                (float)((double)Kxx[(size_t)i * 256 + j] - acc[r][c] + corr);
        }
    }
}

// ---------------------------------------------------------------------------
extern "C" void kernel_launch(void* const* d_in, const int* in_sizes, int n_in,
                              void* d_out, int out_size, void* d_ws, size_t ws_size,
                              hipStream_t stream) {
    const float* X_test = (const float*)d_in[0];
    const float* A_test = (const float*)d_in[1];
    const float* X_obs  = (const float*)d_in[2];
    const float* A_obs  = (const float*)d_in[3];
    const float* ys     = (const float*)d_in[4];
    const float* rho_p  = (const float*)d_in[5];
    const float* g_p    = (const float*)d_in[6];
    const float* nu_p   = (const float*)d_in[7];
    const float* b_p    = (const float*)d_in[8];
    float* out = (float*)d_out;
    char* ws = (char*)d_ws;

    double* Koo  = (double*)(ws + 0);         // 2,097,152 (A; Tbuf alias post-chol)
    double* LL   = (double*)(ws + 2097152);   // 2,097,152 (L row-major; atT/atO overlay pre-chol)
    double* Bc   = (double*)(ws + 4194304);   // 1,052,672 (RHS -> Z)
    float*  KoxT = (float*) (ws + 5246976);   // 524,288
    float*  Kxx  = (float*) (ws + 5771264);   // 262,144
    float*  s1v  = (float*) (ws + 6033408);   // 1,024
    float*  s2v  = (float*) (ws + 6034432);   // 2,048
    double* kbx  = (double*)(ws + 6036480);   // 2,048
    double* Sp   = (double*)(ws + 6038528);   // 1,024 (pad)
    double* Wp   = (double*)(ws + 6039552);   // 36*32768 = 1,179,648
    double* WTp  = (double*)(ws + 7219200);   // 1,179,648 (end 8,398,848)
    double* Tbuf = Koo;                       // aliases dead A after chol
    float*  atT  = (float*)(ws + 2097152);
    float*  atO  = (float*)(ws + 2097152 + 24576);

    self_kernel<<<M + N + 1, 64, 0, stream>>>(X_test, A_test, X_obs, A_obs,
                                              s1v, s2v, atT, atO, Bc);

    gram_kernel<<<dim3(32, 64, 3), 128, 0, stream>>>(X_test, atT, s1v,
                                                     X_obs, atO, s2v,
                                                     rho_p, nu_p, g_p,
                                                     KoxT, Kxx, Koo, Bc);

    factor0_kernel<<<1, 256, 0, stream>>>(Koo, Wp, WTp);
    for (int p = 0; p < 7; ++p) {
        int nb = (7 - p) * (8 - p) / 2 + p;   // trailing tiles + W row-panel p
        upd_kernel<<<nb, 256, 0, stream>>>(Koo, LL, Wp, WTp, p);
    }
    wrow7_kernel<<<7, 256, 0, stream>>>(LL, Wp, WTp);

    gemm1_kernel<<<40, 256, 0, stream>>>(Wp, Bc, Tbuf);
    gemm2_kernel<<<40, 256, 0, stream>>>(WTp, Tbuf, Bc);
    colreduce_kernel<<<65, 256, 0, stream>>>(Bc, ys, b_p, out, kbx, Sp);
    cov_kernel<<<16, 256, 0, stream>>>(Bc, KoxT, Kxx, kbx, Sp, out);
}